// Round 1
// baseline (5104.225 us; speedup 1.0000x reference)
//
#include <hip/hip_runtime.h>
#include <math.h>

// ---------------------------------------------------------------------------
// TbDNet forward, fp32 correctness-first implementation.
// Pipeline: repack weights -> decode programs (device) -> stem1 -> stem2 ->
//           24 generic "round" kernels (module interpreter) -> cls+pool ->
//           fc1 (split-K) -> reduce -> fc2.
// ---------------------------------------------------------------------------

#define MAXR 24

// ws layout (float offsets)
static const size_t O_WSTEM1 = 0;          // 9*1024*128   = 1179648
static const size_t O_WMOD   = 1179648;    // 9 sets * 9*128*128 = 1327104
static const size_t O_WSTEM2 = 2506752;    // 147456
static const size_t O_CLSWT  = 2654208;    // 131072  [ic][1024]
static const size_t O_STEM   = 2785280;    // 64*128*196 = 1605632
static const size_t O_XA     = 4390912;    // 1605632
static const size_t O_XB     = 5996544;    // 1605632
static const size_t O_FEAT   = 7602176;    // 1605632
static const size_t O_ATTN   = 9207808;    // 64*196
static const size_t O_SAVED  = 9220352;    // 64*196
static const size_t O_FC1T   = 9232896;    // 1024*64
static const size_t O_SCHED  = 9298432;    // 64*MAXR ints
static const size_t O_ACT    = O_XA;       // alias: pooled act [64][50176] = 3211264 = XA+XB
static const size_t O_FC1P   = O_FEAT;     // alias: fc1 partials 16*1024*64 = 1048576

// encoding: op | wset<<4 | dil<<8 | gate<<12 | src<<13 | dst<<15
// op: 0 NOP, 1 SCENE, 2 INTERSECT, 3 CONV3, 4 CONV1x1SIG
// src/dst: 0 XA, 1 XB, 2 FEAT, 3 STEM(gated)

struct RepackArgs { const float* src[12]; };

__global__ __launch_bounds__(256) void k_repack(RepackArgs a, float* ws)
{
    const int y = blockIdx.y;
    const float* __restrict__ src = a.src[y];
    int gid = blockIdx.x * 256 + threadIdx.x;
    int gsz = gridDim.x * 256;
    if (y == 11) {                       // cls_w [1024][128] -> [128][1024]
        float* dst = ws + O_CLSWT;
        for (int i = gid; i < 131072; i += gsz) {
            int ic = i >> 10, p = i & 1023;
            dst[i] = src[p * 128 + ic];
        }
    } else {
        int IC = (y == 0) ? 1024 : 128;
        float* dst = ws + ((y == 0) ? O_WSTEM1 : (y == 1) ? O_WSTEM2
                                               : O_WMOD + (size_t)(y - 2) * 147456);
        int total = 9 * IC * 128;
        for (int i = gid; i < total; i += gsz) {
            // dst linear: i = (t*IC + ic)*128 + oc
            int oc = i & 127;
            int r  = i >> 7;
            int ic = r & (IC - 1);
            int t  = r / IC;
            dst[i] = src[((size_t)oc * IC + ic) * 9 + t];
        }
    }
}

__global__ __launch_bounds__(256) void k_decode_init(const int* __restrict__ prog, float* ws)
{
    int gid = blockIdx.x * 256 + threadIdx.x;
    int gsz = gridDim.x * 256;
    for (int i = gid; i < 64 * 196; i += gsz) { ws[O_ATTN + i] = 1.0f; ws[O_SAVED + i] = 1.0f; }
    for (int i = gid; i < 64 * 25088; i += gsz) ws[O_FEAT + i] = 0.0f;
    if (gid < 64) {
        int n = gid;
        int ent[MAXR];
        for (int r = 0; r < MAXR; ++r) ent[r] = 0;
        int rc = 0;
#define ENC(op,wv,dl,g,s,d) ((op)|((wv)<<4)|((dl)<<8)|((g)<<12)|((s)<<13)|((d)<<15))
#define EMIT(v) do { if (rc < MAXR) ent[rc++] = (v); } while (0)
        for (int j = 7; j >= 0; --j) {
            int t = prog[n * 8 + j];
            switch (t) {
                case 3: EMIT(ENC(1,0,0,0,0,0)); break;  // SCENE
                case 4: EMIT(ENC(2,0,0,0,0,0)); break;  // INTERSECT
                case 5:                                  // FILT
                    EMIT(ENC(3,0,1,1,3,0));
                    EMIT(ENC(3,1,1,0,0,1));
                    EMIT(ENC(4,0,0,0,1,0));
                    break;
                case 6:                                  // RELATE
                    EMIT(ENC(3,2,1,1,3,0));
                    EMIT(ENC(3,3,2,0,0,1));
                    EMIT(ENC(3,4,4,0,1,0));
                    EMIT(ENC(3,5,8,0,0,1));
                    EMIT(ENC(3,6,1,0,1,0));
                    EMIT(ENC(4,1,0,0,0,0));
                    break;
                case 7:                                  // QUERY
                    EMIT(ENC(3,7,1,1,3,0));
                    EMIT(ENC(3,8,1,0,0,2));
                    break;
                default: break;                          // PAD/START/END
            }
        }
#undef EMIT
#undef ENC
        int* sched = (int*)(ws + O_SCHED);
        for (int r = 0; r < MAXR; ++r) sched[n * MAXR + r] = ent[r];
    }
}

__device__ __forceinline__ int pcenter(int p)
{
    int y = p / 14, x = p - y * 14;
    return (y + 8) * 30 + (x + 8);
}

// 3x3 dilated conv, one sample, 32 output channels [oc0,oc0+32), bias+relu.
// src: [ICtot][196] sample base. wrep: [9][ICtot][128]. attn: [196] gate or null.
__device__ void conv_core(const float* __restrict__ src,
                          const float* __restrict__ wrep,
                          const float* __restrict__ bias,
                          float* __restrict__ dst,
                          const float* __restrict__ attn,
                          int ICtot, int dil, int oc0, float* sm)
{
    float* s_src = sm;            // 8*900 zero-padded 30x30 tiles
    float* s_w   = sm + 7200;     // 8*9*32
    float* s_at  = sm + 7200 + 2304; // 196
    const int tid  = threadIdx.x;
    const int lane = tid & 63, wave = tid >> 6;

    for (int i = tid; i < 7200; i += 256) s_src[i] = 0.0f;
    if (attn) for (int i = tid; i < 196; i += 256) s_at[i] = attn[i];
    __syncthreads();

    const int px0 = lane, px1 = lane + 64, px2 = lane + 128;
    const int c0 = pcenter(px0), c1 = pcenter(px1), c2 = pcenter(px2);
    const int pxi = lane >> 3, ocr = lane & 7;
    const int vx = (pxi < 4);
    const int cx = pcenter(192 + (vx ? pxi : 0));
    int toff[9];
#pragma unroll
    for (int t = 0; t < 9; ++t) {
        int dy = t / 3 - 1, dx = t - (t / 3) * 3 - 1;
        toff[t] = (dy * 30 + dx) * dil;
    }

    float acc0[8] = {}, acc1[8] = {}, acc2[8] = {};
    float accx = 0.0f;

    for (int cb = 0; cb < ICtot; cb += 8) {
        for (int i = tid; i < 8 * 196; i += 256) {
            int c = i / 196, p = i - c * 196;
            int y = p / 14, x = p - y * 14;
            float v = src[(size_t)(cb + c) * 196 + p];
            if (attn) v *= s_at[p];
            s_src[c * 900 + (y + 8) * 30 + (x + 8)] = v;
        }
        for (int i = tid; i < 8 * 288; i += 256) {
            int c = i / 288, r = i - c * 288;
            int t = r >> 5, o = r & 31;
            s_w[i] = wrep[((size_t)t * ICtot + cb + c) * 128 + oc0 + o];
        }
        __syncthreads();
#pragma unroll 4
        for (int c = 0; c < 8; ++c) {
            const float* sc = s_src + c * 900;
            const float* wc = s_w + c * 288 + (wave << 3);
#pragma unroll
            for (int t = 0; t < 9; ++t) {
                float wreg[8];
                *reinterpret_cast<float4*>(&wreg[0]) = *reinterpret_cast<const float4*>(wc + t * 32);
                *reinterpret_cast<float4*>(&wreg[4]) = *reinterpret_cast<const float4*>(wc + t * 32 + 4);
                const int of = toff[t];
                float s0 = sc[c0 + of], s1 = sc[c1 + of], s2 = sc[c2 + of];
                float sx = sc[cx + of];
                float wx = wc[t * 32 + ocr];
#pragma unroll
                for (int o = 0; o < 8; ++o) {
                    acc0[o] = fmaf(s0, wreg[o], acc0[o]);
                    acc1[o] = fmaf(s1, wreg[o], acc1[o]);
                    acc2[o] = fmaf(s2, wreg[o], acc2[o]);
                }
                accx = fmaf(sx, wx, accx);
            }
        }
        __syncthreads();
    }

    const int ocb = oc0 + (wave << 3);
#pragma unroll
    for (int o = 0; o < 8; ++o) {
        float b = bias[ocb + o];
        dst[(size_t)(ocb + o) * 196 + px0] = fmaxf(acc0[o] + b, 0.0f);
        dst[(size_t)(ocb + o) * 196 + px1] = fmaxf(acc1[o] + b, 0.0f);
        dst[(size_t)(ocb + o) * 196 + px2] = fmaxf(acc2[o] + b, 0.0f);
    }
    if (vx)
        dst[(size_t)(ocb + ocr) * 196 + 192 + pxi] = fmaxf(accx + bias[ocb + ocr], 0.0f);
}

__global__ __launch_bounds__(256) void k_conv_fixed(const float* __restrict__ src_base,
                                                    const float* __restrict__ wrep,
                                                    const float* __restrict__ bias,
                                                    float* __restrict__ dst_base, int ICtot)
{
    __shared__ float sm[9700];
    int n = blockIdx.x >> 2, oct = blockIdx.x & 3;
    conv_core(src_base + (size_t)n * ICtot * 196, wrep, bias,
              dst_base + (size_t)n * 25088, nullptr, ICtot, 1, oct * 32, sm);
}

struct RArgs {
    float* ws;
    const float* mbias[9];
    const float* w1x1[2];
    const float* b1x1[2];
};

__global__ __launch_bounds__(256) void k_round(RArgs a, int r)
{
    __shared__ float sm[9700];
    const int n = blockIdx.x >> 2, oct = blockIdx.x & 3;
    float* ws = a.ws;
    const int* sched = (const int*)(ws + O_SCHED);
    int e = sched[n * MAXR + r];
    int op = e & 15;
    if (op == 0) return;
    float* attn  = ws + O_ATTN + n * 196;
    float* saved = ws + O_SAVED + n * 196;
    if (op == 1) {                        // SCENE
        if (oct == 0 && threadIdx.x < 196) {
            int p = threadIdx.x;
            saved[p] = attn[p];
            attn[p] = 1.0f;
        }
        return;
    }
    if (op == 2) {                        // INTERSECT
        if (oct == 0 && threadIdx.x < 196) {
            int p = threadIdx.x;
            attn[p] = fminf(attn[p], saved[p]);
        }
        return;
    }
    int wset = (e >> 4) & 15, dil = (e >> 8) & 15, gate = (e >> 12) & 1;
    int srcid = (e >> 13) & 3, dstid = (e >> 15) & 3;
    const float* src = ws + (srcid == 3 ? O_STEM : (srcid == 1 ? O_XB : O_XA)) + (size_t)n * 25088;
    if (op == 4) {                        // conv1x1 + sigmoid -> attn
        if (oct == 0 && threadIdx.x < 196) {
            int p = threadIdx.x;
            const float* w = a.w1x1[wset];
            float acc = a.b1x1[wset][0];
#pragma unroll 8
            for (int ic = 0; ic < 128; ++ic) acc += w[ic] * src[ic * 196 + p];
            attn[p] = 1.0f / (1.0f + __expf(-acc));
        }
        return;
    }
    // CONV3
    float* dst = ws + (dstid == 2 ? O_FEAT : (dstid == 1 ? O_XB : O_XA)) + (size_t)n * 25088;
    conv_core(src, ws + O_WMOD + (size_t)wset * 147456, a.mbias[wset], dst,
              gate ? attn : nullptr, 128, dil, oct * 32, sm);
}

// cls conv1x1 (128->1024) + relu + 2x2 maxpool, per block: (sample, 32-p tile)
__global__ __launch_bounds__(256) void k_cls_pool(const float* __restrict__ feat_base,
                                                  const float* __restrict__ clsT,
                                                  const float* __restrict__ cls_b,
                                                  float* __restrict__ act)
{
    __shared__ float s_src[3136];   // 16*196
    __shared__ float s_w[512];      // 16*32
    __shared__ float s_out[6272];   // 32*196
    const int n = blockIdx.x >> 5, pt = blockIdx.x & 31;
    const int tid = threadIdx.x, lane = tid & 63, wave = tid >> 6;
    const float* feat = feat_base + (size_t)n * 25088;
    const int p0 = lane, p1 = lane + 64, p2 = lane + 128;
    const int pxi = lane >> 3, ocr = lane & 7;
    const int vx = (pxi < 4);
    const int pxx = 192 + (vx ? pxi : 0);
    float acc0[8] = {}, acc1[8] = {}, acc2[8] = {};
    float accx = 0.0f;
    for (int cb = 0; cb < 128; cb += 16) {
        for (int i = tid; i < 3136; i += 256) s_src[i] = feat[cb * 196 + i];
        for (int i = tid; i < 512; i += 256) {
            int c = i >> 5, o = i & 31;
            s_w[i] = clsT[(size_t)(cb + c) * 1024 + pt * 32 + o];
        }
        __syncthreads();
#pragma unroll 4
        for (int c = 0; c < 16; ++c) {
            const float* sc = s_src + c * 196;
            const float* wc = s_w + c * 32 + (wave << 3);
            float wreg[8];
            *reinterpret_cast<float4*>(&wreg[0]) = *reinterpret_cast<const float4*>(wc);
            *reinterpret_cast<float4*>(&wreg[4]) = *reinterpret_cast<const float4*>(wc + 4);
            float s0 = sc[p0], s1 = sc[p1], s2 = sc[p2], sx = sc[pxx];
            float wx = wc[ocr];
#pragma unroll
            for (int o = 0; o < 8; ++o) {
                acc0[o] = fmaf(s0, wreg[o], acc0[o]);
                acc1[o] = fmaf(s1, wreg[o], acc1[o]);
                acc2[o] = fmaf(s2, wreg[o], acc2[o]);
            }
            accx = fmaf(sx, wx, accx);
        }
        __syncthreads();
    }
    const int pb = wave << 3;
#pragma unroll
    for (int o = 0; o < 8; ++o) {
        float b = cls_b[pt * 32 + pb + o];
        s_out[(pb + o) * 196 + p0] = fmaxf(acc0[o] + b, 0.0f);
        s_out[(pb + o) * 196 + p1] = fmaxf(acc1[o] + b, 0.0f);
        s_out[(pb + o) * 196 + p2] = fmaxf(acc2[o] + b, 0.0f);
    }
    if (vx) s_out[(pb + ocr) * 196 + pxx] = fmaxf(accx + cls_b[pt * 32 + pb + ocr], 0.0f);
    __syncthreads();
    for (int i = tid; i < 32 * 49; i += 256) {
        int p = i / 49, pp = i - p * 49;
        int py = pp / 7, px = pp - py * 7;
        const float* o = s_out + p * 196 + py * 28 + px * 2;
        float m = fmaxf(fmaxf(o[0], o[1]), fmaxf(o[14], o[15]));
        act[(size_t)n * 50176 + (size_t)(pt * 32 + p) * 49 + pp] = m;
    }
}

// fc1 split-K: block = (jt 0..15, ks 0..15); out partial[ks][j][n]
__global__ __launch_bounds__(256) void k_fc1p(const float* __restrict__ act,
                                              const float* __restrict__ w,
                                              float* __restrict__ part)
{
    __shared__ float s_a[64 * 65];
    const int jt = blockIdx.x & 15, ks = blockIdx.x >> 4;
    const int j0 = jt * 64, k0 = ks * 3136;
    const int tid = threadIdx.x, lane = tid & 63, wave = tid >> 6;
    const int kl = tid & 63, nl = tid >> 6;
    float acc[16] = {};
    const int jbase = __builtin_amdgcn_readfirstlane(j0 + wave * 16);
    for (int kc = 0; kc < 3136; kc += 64) {
        __syncthreads();
        for (int nn = nl; nn < 64; nn += 4)
            s_a[kl * 65 + nn] = act[(size_t)nn * 50176 + k0 + kc + kl];
        __syncthreads();
        const float* wbase = w + (size_t)jbase * 50176 + k0 + kc;
#pragma unroll 4
        for (int k = 0; k < 64; ++k) {
            float a = s_a[k * 65 + lane];
#pragma unroll
            for (int jj = 0; jj < 16; ++jj)
                acc[jj] = fmaf(a, wbase[(size_t)jj * 50176 + k], acc[jj]);
        }
    }
    for (int jj = 0; jj < 16; ++jj)
        part[((size_t)ks * 1024 + jbase + jj) * 64 + lane] = acc[jj];
}

__global__ __launch_bounds__(256) void k_fc1r(const float* __restrict__ part,
                                              const float* __restrict__ b,
                                              float* __restrict__ fc1T)
{
    int i = blockIdx.x * 256 + threadIdx.x;
    if (i >= 65536) return;
    float s = 0.0f;
    for (int ks = 0; ks < 16; ++ks) s += part[(size_t)ks * 65536 + i];
    int j = i >> 6;
    fc1T[i] = fmaxf(s + b[j], 0.0f);
}

__global__ __launch_bounds__(256) void k_fc2(const float* __restrict__ fc1T,
                                             const float* __restrict__ w,
                                             const float* __restrict__ b,
                                             float* __restrict__ out)
{
    __shared__ float red[256];
    const int a_ = blockIdx.x;         // 28
    const int tid = threadIdx.x, lane = tid & 63, q = tid >> 6;
    float acc = 0.0f;
    const float* wr = w + (size_t)a_ * 1024;
    for (int k = q * 256; k < q * 256 + 256; ++k)
        acc = fmaf(fc1T[k * 64 + lane], wr[k], acc);
    red[tid] = acc;
    __syncthreads();
    if (q == 0) {
        float s = red[tid] + red[tid + 64] + red[tid + 128] + red[tid + 192] + b[a_];
        out[lane * 28 + a_] = s;
    }
}

extern "C" void kernel_launch(void* const* d_in, const int* in_sizes, int n_in,
                              void* d_out, int out_size, void* d_ws, size_t ws_size,
                              hipStream_t stream)
{
    const float* feats = (const float*)d_in[0];
    const int*   prog  = (const int*)d_in[1];
    float* ws  = (float*)d_ws;
    float* out = (float*)d_out;

    RepackArgs ra;
    ra.src[0]  = (const float*)d_in[2];   // stem_w1
    ra.src[1]  = (const float*)d_in[4];   // stem_w2
    ra.src[2]  = (const float*)d_in[6];   // att_w1
    ra.src[3]  = (const float*)d_in[8];   // att_w2
    ra.src[4]  = (const float*)d_in[12];  // rel_w1
    ra.src[5]  = (const float*)d_in[14];  // rel_w2
    ra.src[6]  = (const float*)d_in[16];  // rel_w3
    ra.src[7]  = (const float*)d_in[18];  // rel_w4
    ra.src[8]  = (const float*)d_in[20];  // rel_w5
    ra.src[9]  = (const float*)d_in[24];  // qry_w1
    ra.src[10] = (const float*)d_in[26];  // qry_w2
    ra.src[11] = (const float*)d_in[28];  // cls_w

    k_repack<<<dim3(64, 12), 256, 0, stream>>>(ra, ws);
    k_decode_init<<<256, 256, 0, stream>>>(prog, ws);

    // stem1: feats -> XA ; stem2: XA -> STEM
    k_conv_fixed<<<256, 256, 0, stream>>>(feats, ws + O_WSTEM1, (const float*)d_in[3],
                                          ws + O_XA, 1024);
    k_conv_fixed<<<256, 256, 0, stream>>>(ws + O_XA, ws + O_WSTEM2, (const float*)d_in[5],
                                          ws + O_STEM, 128);

    RArgs ga;
    ga.ws = ws;
    ga.mbias[0] = (const float*)d_in[7];   // att_b1
    ga.mbias[1] = (const float*)d_in[9];   // att_b2
    ga.mbias[2] = (const float*)d_in[13];  // rel_b1
    ga.mbias[3] = (const float*)d_in[15];  // rel_b2
    ga.mbias[4] = (const float*)d_in[17];  // rel_b3
    ga.mbias[5] = (const float*)d_in[19];  // rel_b4
    ga.mbias[6] = (const float*)d_in[21];  // rel_b5
    ga.mbias[7] = (const float*)d_in[25];  // qry_b1
    ga.mbias[8] = (const float*)d_in[27];  // qry_b2
    ga.w1x1[0]  = (const float*)d_in[10];  // att_w3
    ga.w1x1[1]  = (const float*)d_in[22];  // rel_w6
    ga.b1x1[0]  = (const float*)d_in[11];  // att_b3
    ga.b1x1[1]  = (const float*)d_in[23];  // rel_b6

    for (int r = 0; r < MAXR; ++r)
        k_round<<<256, 256, 0, stream>>>(ga, r);

    k_cls_pool<<<2048, 256, 0, stream>>>(ws + O_FEAT, ws + O_CLSWT,
                                         (const float*)d_in[29], ws + O_ACT);
    k_fc1p<<<256, 256, 0, stream>>>(ws + O_ACT, (const float*)d_in[30], ws + O_FC1P);
    k_fc1r<<<256, 256, 0, stream>>>(ws + O_FC1P, (const float*)d_in[31], ws + O_FC1T);
    k_fc2<<<28, 256, 0, stream>>>(ws + O_FC1T, (const float*)d_in[32],
                                  (const float*)d_in[33], out);
}

// Round 2
// 1154.234 us; speedup vs baseline: 4.4222x; 4.4222x over previous
//
#include <hip/hip_runtime.h>
#include <math.h>

// ---------------------------------------------------------------------------
// TbDNet forward, round 2: all 3x3 convs + cls 1x1 on bf16 MFMA (16x16x32).
// Activations pixel-major [196][128] bf16. fc1/fc2 stay fp32 (HBM-bound).
// ---------------------------------------------------------------------------

typedef __attribute__((ext_vector_type(8)))  short   short8;
typedef __attribute__((ext_vector_type(8)))  __bf16  bf16x8;
typedef __attribute__((ext_vector_type(4)))  float   f32x4;

#define NROUNDS 16

// byte offsets in ws
#define B_WSTEM1 0UL                 // bf16 [9][128][1024]
#define B_WSTEM2 2359296UL           // bf16 [9][128][128]
#define B_WMOD   2654208UL           // 9 x bf16 [9][128][128]
#define B_WCLS   5308416UL           // bf16 [1024][128]
#define B_STEM   5570560UL           // bf16 [64][196][128]
#define B_XA     8781824UL
#define B_XB     11993088UL
#define B_FEAT   15204352UL
#define B_ATTN   18415616UL          // f32 [64][196]
#define B_SAVED  18465792UL
#define B_SCHED  18515968UL          // int [64][NROUNDS]
#define B_ACT    18520064UL          // f32 [64][50176]
#define B_FC1P   31365120UL          // f32 [16][1024][64]
#define B_FC1T   35559424UL          // f32 [1024][64]

__device__ __forceinline__ unsigned short f2bf(float f) {
    unsigned int b = __float_as_uint(f);
    b += 0x7fffu + ((b >> 16) & 1u);          // RNE
    return (unsigned short)(b >> 16);
}
__device__ __forceinline__ float bf2f(unsigned short u) {
    return __uint_as_float(((unsigned int)u) << 16);
}
__device__ __forceinline__ f32x4 mfma16(bf16x8 a, bf16x8 b, f32x4 c) {
    return __builtin_amdgcn_mfma_f32_16x16x32_bf16(a, b, c, 0, 0, 0);
}

// ---------------------------------------------------------------------------
// Weight repack: conv sets -> [tap][oc][ic] bf16; cls_w -> straight bf16.
// ---------------------------------------------------------------------------
struct RepackArgs { const float* src[12]; };

__global__ __launch_bounds__(256) void k_repack(RepackArgs a, char* ws)
{
    const int y = blockIdx.y;
    const float* __restrict__ src = a.src[y];
    int gid = blockIdx.x * 256 + threadIdx.x;
    int gsz = gridDim.x * 256;
    if (y == 11) {
        unsigned short* dst = (unsigned short*)(ws + B_WCLS);
        for (int i = gid; i < 131072; i += gsz) dst[i] = f2bf(src[i]);
    } else {
        const int IC = (y == 0) ? 1024 : 128;
        const int lg = (y == 0) ? 10 : 7;
        unsigned short* dst = (unsigned short*)(ws + ((y == 0) ? B_WSTEM1
                                    : (y == 1) ? B_WSTEM2
                                    : B_WMOD + (size_t)(y - 2) * 294912));
        const int total = 9 << (lg + 7);
        for (int i = gid; i < total; i += gsz) {
            int ic = i & (IC - 1);
            int oc = (i >> lg) & 127;
            int t  = i >> (lg + 7);
            dst[i] = f2bf(src[((size_t)oc * IC + ic) * 9 + t]);
        }
    }
}

// ---------------------------------------------------------------------------
// Program decode + state init.
// encoding: op | wset<<4 | dil<<8 | gate<<12 | src<<13 | dst<<15
// op: 0 NOP, 1 SCENE, 2 INTERSECT, 3 CONV3, 4 CONV1x1SIG
// src/dst ids: 0 XA, 1 XB, 2 FEAT, 3 STEM
// ---------------------------------------------------------------------------
__global__ __launch_bounds__(256) void k_decode_init(const int* __restrict__ prog, char* ws)
{
    int gid = blockIdx.x * 256 + threadIdx.x;
    int gsz = gridDim.x * 256;
    float* attn  = (float*)(ws + B_ATTN);
    float* saved = (float*)(ws + B_SAVED);
    for (int i = gid; i < 64 * 196; i += gsz) { attn[i] = 1.0f; saved[i] = 1.0f; }
    unsigned int* fz = (unsigned int*)(ws + B_FEAT);
    for (int i = gid; i < 64 * 25088 / 2; i += gsz) fz[i] = 0u;
    if (gid < 64) {
        int n = gid;
        int ent[NROUNDS];
        for (int r = 0; r < NROUNDS; ++r) ent[r] = 0;
        int rc = 0;
#define ENC(op,wv,dl,g,s,d) ((op)|((wv)<<4)|((dl)<<8)|((g)<<12)|((s)<<13)|((d)<<15))
#define EMIT(v) do { if (rc < NROUNDS) ent[rc++] = (v); } while (0)
        for (int j = 7; j >= 0; --j) {
            int t = prog[n * 8 + j];
            switch (t) {
                case 3: EMIT(ENC(1,0,0,0,0,0)); break;  // SCENE
                case 4: EMIT(ENC(2,0,0,0,0,0)); break;  // INTERSECT
                case 5:                                  // FILT
                    EMIT(ENC(3,0,1,1,3,0));
                    EMIT(ENC(3,1,1,0,0,1));
                    EMIT(ENC(4,0,0,0,1,0));
                    break;
                case 6:                                  // RELATE
                    EMIT(ENC(3,2,1,1,3,0));
                    EMIT(ENC(3,3,2,0,0,1));
                    EMIT(ENC(3,4,4,0,1,0));
                    EMIT(ENC(3,5,8,0,0,1));
                    EMIT(ENC(3,6,1,0,1,0));
                    EMIT(ENC(4,1,0,0,0,0));
                    break;
                case 7:                                  // QUERY
                    EMIT(ENC(3,7,1,1,3,0));
                    EMIT(ENC(3,8,1,0,0,2));
                    break;
                default: break;
            }
        }
#undef EMIT
#undef ENC
        int* sched = (int*)(ws + B_SCHED);
        for (int r = 0; r < NROUNDS; ++r) sched[n * NROUNDS + r] = ent[r];
    }
}

// ---------------------------------------------------------------------------
// MFMA 3x3 dilated conv core.
// Block: (sample, oc-half 64, px-half 112). 4 waves: wm=oc32-half, wn=px interleave.
// LDS image: [197 rows][136 ic] bf16 (row 196 = zero page for invalid taps).
// A (weights) from global [9][128][ICtot] bf16; B from LDS; acc fp32.
// ---------------------------------------------------------------------------
__device__ void conv_mfma_core(const unsigned short* __restrict__ srcB,  // bf16 [196][128] or null
                               const float*  __restrict__ srcF,          // f32 [ICtot][196] or null
                               const float*  __restrict__ gate,          // [196] or null
                               const unsigned short* __restrict__ wrep,  // bf16 [9][128][ICtot]
                               const float*  __restrict__ bias,          // [128]
                               unsigned short* __restrict__ dst,         // bf16 [196][128]
                               int ICtot, int dil, int och, int pxh,
                               unsigned short* s_img)
{
    const int tid  = threadIdx.x, lane = tid & 63;
    const int w    = tid >> 6, wm = w & 1, wn = w >> 1;
    const int l15  = lane & 15, lq = lane >> 4;

    if (tid < 68) ((unsigned int*)s_img)[196 * 68 + tid] = 0u;   // zero page row

    int pglob[4], pbyt[4], pyv[4], pxv[4];
#pragma unroll
    for (int j = 0; j < 4; ++j) {
        int nt = wn + 2 * j;
        int p  = (pxh * 7 + nt) * 16 + l15;
        pglob[j] = p;
        int py = p / 14;
        pyv[j] = (p < 196) ? py : 10000;
        pxv[j] = p - py * 14;
        pbyt[j] = p * 272 + lq * 16;
    }
    const int zaddr = 196 * 272 + lq * 16;
    const int nNT = (wn == 0) ? 4 : 3;

    f32x4 acc[2][4];
#pragma unroll
    for (int m = 0; m < 2; ++m)
#pragma unroll
        for (int j = 0; j < 4; ++j) acc[m][j] = (f32x4){0.f, 0.f, 0.f, 0.f};

    const unsigned short* wlane = wrep + (size_t)(och * 64 + wm * 32 + l15) * ICtot + lq * 8;
    const int nslab = ICtot >> 7;

    for (int slab = 0; slab < nslab; ++slab) {
        if (slab) __syncthreads();
        if (srcF) {                                   // fp32 C-major source (stem1)
            const float* sf = srcF + slab * 128 * 196;
            for (int i = tid; i < 128 * 196; i += 256) {
                int ic = i / 196, p = i - ic * 196;
                s_img[p * 136 + ic] = f2bf(sf[i]);
            }
        } else if (gate) {                            // bf16 source, gated
            for (int i = tid; i < 196 * 16; i += 256) {
                int p = i >> 4, c8 = (i & 15) * 8;
                short8 v = *(const short8*)(srcB + p * 128 + c8);
                float g = gate[p];
                short8 ov;
#pragma unroll
                for (int e = 0; e < 8; ++e)
                    ov[e] = (short)f2bf(bf2f((unsigned short)v[e]) * g);
                *(short8*)(s_img + p * 136 + c8) = ov;
            }
        } else {                                      // bf16 source, plain copy
            for (int i = tid; i < 196 * 16; i += 256) {
                int p = i >> 4, c8 = (i & 15) * 8;
                *(short8*)(s_img + p * 136 + c8) = *(const short8*)(srcB + p * 128 + c8);
            }
        }
        __syncthreads();

        const unsigned short* wslab = wlane + slab * 128;
#pragma unroll
        for (int t = 0; t < 9; ++t) {
            const int dy = (t / 3 - 1) * dil, dx = (t % 3 - 1) * dil;
            const int tb = (dy * 14 + dx) * 272;
            int baddr[4];
#pragma unroll
            for (int j = 0; j < 4; ++j) {
                int yy = pyv[j] + dy, xx = pxv[j] + dx;
                bool ok = ((unsigned)yy < 14u) && ((unsigned)xx < 14u);
                baddr[j] = ok ? (pbyt[j] + tb) : zaddr;
            }
            const unsigned short* wt = wslab + (size_t)(t * 128) * ICtot;
#pragma unroll
            for (int kc = 0; kc < 4; ++kc) {
                bf16x8 a0 = *(const bf16x8*)(wt + kc * 32);
                bf16x8 a1 = *(const bf16x8*)(wt + (size_t)16 * ICtot + kc * 32);
#pragma unroll
                for (int j = 0; j < 4; ++j) {
                    if (j < nNT) {
                        bf16x8 b = *(const bf16x8*)((const char*)s_img + baddr[j] + kc * 64);
                        acc[0][j] = mfma16(a0, b, acc[0][j]);
                        acc[1][j] = mfma16(a1, b, acc[1][j]);
                    }
                }
            }
        }
    }

    // epilogue: bias + relu -> bf16 [196][128]
#pragma unroll
    for (int m = 0; m < 2; ++m) {
        const int oc = och * 64 + wm * 32 + m * 16 + lq * 4;
        const float4 b4 = *(const float4*)(bias + oc);
#pragma unroll
        for (int j = 0; j < 4; ++j) {
            if (j < nNT) {
                int p = pglob[j];
                if (p < 196) {
                    float v0 = fmaxf(acc[m][j][0] + b4.x, 0.f);
                    float v1 = fmaxf(acc[m][j][1] + b4.y, 0.f);
                    float v2 = fmaxf(acc[m][j][2] + b4.z, 0.f);
                    float v3 = fmaxf(acc[m][j][3] + b4.w, 0.f);
                    unsigned int lo = (unsigned int)f2bf(v0) | ((unsigned int)f2bf(v1) << 16);
                    unsigned int hi = (unsigned int)f2bf(v2) | ((unsigned int)f2bf(v3) << 16);
                    uint2 pk; pk.x = lo; pk.y = hi;
                    *(uint2*)(dst + p * 128 + oc) = pk;
                }
            }
        }
    }
}

__global__ __launch_bounds__(256) void k_conv_stem(const float* __restrict__ featsF,
                                                   const unsigned short* __restrict__ wrep,
                                                   const float* __restrict__ bias,
                                                   unsigned short* __restrict__ dstall,
                                                   int ICtot,
                                                   const unsigned short* __restrict__ srcBall)
{
    __shared__ unsigned short s_img[197 * 136];
    const int n = blockIdx.x >> 2, och = (blockIdx.x >> 1) & 1, pxh = blockIdx.x & 1;
    if (ICtot == 1024)
        conv_mfma_core(nullptr, featsF + (size_t)n * 1024 * 196, nullptr, wrep, bias,
                       dstall + (size_t)n * 25088, 1024, 1, och, pxh, s_img);
    else
        conv_mfma_core(srcBall + (size_t)n * 25088, nullptr, nullptr, wrep, bias,
                       dstall + (size_t)n * 25088, 128, 1, och, pxh, s_img);
}

// ---------------------------------------------------------------------------
// Module interpreter round.
// ---------------------------------------------------------------------------
struct RArgs {
    char* ws;
    const float* mbias[9];
    const float* w1x1[2];
    const float* b1x1[2];
};

__global__ __launch_bounds__(256) void k_round(RArgs a, int r)
{
    __shared__ unsigned short s_img[197 * 136];
    const int bx = blockIdx.x;
    const int n = bx >> 2, och = (bx >> 1) & 1, pxh = bx & 1;
    char* ws = a.ws;
    const int* sched = (const int*)(ws + B_SCHED);
    const int e = sched[n * NROUNDS + r];
    const int op = e & 15;
    if (op == 0) return;
    float* attn  = (float*)(ws + B_ATTN)  + n * 196;
    float* saved = (float*)(ws + B_SAVED) + n * 196;
    if (op == 1 || op == 2) {
        if ((bx & 3) == 0 && threadIdx.x < 196) {
            int p = threadIdx.x;
            if (op == 1) { saved[p] = attn[p]; attn[p] = 1.0f; }
            else         attn[p] = fminf(attn[p], saved[p]);
        }
        return;
    }
    const int wset = (e >> 4) & 15, dil = (e >> 8) & 15, gatef = (e >> 12) & 1;
    const int srcid = (e >> 13) & 3, dstid = (e >> 15) & 3;
    const unsigned short* src = (const unsigned short*)(ws +
            (srcid == 3 ? B_STEM : srcid == 1 ? B_XB : B_XA)) + (size_t)n * 25088;
    if (op == 4) {                                  // conv1x1 + sigmoid -> attn
        if ((bx & 3) == 0 && threadIdx.x < 196) {
            int p = threadIdx.x;
            const float* wv = a.w1x1[wset];
            float acc = a.b1x1[wset][0];
            const unsigned short* row = src + p * 128;
#pragma unroll 8
            for (int ic = 0; ic < 128; ++ic) acc += bf2f(row[ic]) * wv[ic];
            attn[p] = 1.0f / (1.0f + __expf(-acc));
        }
        return;
    }
    unsigned short* dst = (unsigned short*)(ws +
            (dstid == 2 ? B_FEAT : dstid == 1 ? B_XB : B_XA)) + (size_t)n * 25088;
    const unsigned short* wrep = (const unsigned short*)(ws + B_WMOD) + (size_t)wset * 9 * 128 * 128;
    conv_mfma_core(src, nullptr, gatef ? attn : nullptr, wrep, a.mbias[wset], dst,
                   128, dil, och, pxh, s_img);
}

// ---------------------------------------------------------------------------
// cls 1x1 conv (128->1024, MFMA) + bias + relu + 2x2 maxpool -> act f32.
// Block: (sample, 64-P tile). Wave w owns Mtile w (16 P) x all 14 Ntiles.
// ---------------------------------------------------------------------------
__global__ __launch_bounds__(256) void k_cls_pool(const unsigned short* __restrict__ featall,
                                                  const unsigned short* __restrict__ clsw,
                                                  const float* __restrict__ clsb,
                                                  float* __restrict__ act)
{
    __shared__ char smem[197 * 272 + 64 * 200 * 4];
    unsigned short* s_img = (unsigned short*)smem;
    float* s_pool = (float*)(smem + 197 * 272);
    const int n = blockIdx.x >> 4, pt = blockIdx.x & 15;
    const int tid = threadIdx.x, lane = tid & 63, w = tid >> 6;
    const int l15 = lane & 15, lq = lane >> 4;
    const unsigned short* feat = featall + (size_t)n * 25088;

    if (tid < 68) ((unsigned int*)s_img)[196 * 68 + tid] = 0u;
    for (int i = tid; i < 196 * 16; i += 256) {
        int p = i >> 4, c8 = (i & 15) * 8;
        *(short8*)(s_img + p * 136 + c8) = *(const short8*)(feat + p * 128 + c8);
    }
    f32x4 acc[14];
#pragma unroll
    for (int j = 0; j < 14; ++j) acc[j] = (f32x4){0.f, 0.f, 0.f, 0.f};
    __syncthreads();

    const unsigned short* wl = clsw + (size_t)(pt * 64 + w * 16 + l15) * 128 + lq * 8;
#pragma unroll
    for (int kc = 0; kc < 4; ++kc) {
        bf16x8 a0 = *(const bf16x8*)(wl + kc * 32);
#pragma unroll
        for (int j = 0; j < 14; ++j) {
            int p = j * 16 + l15;
            int ba = (p < 196) ? (p * 272 + lq * 16 + kc * 64) : (196 * 272 + lq * 16);
            bf16x8 b = *(const bf16x8*)((const char*)s_img + ba);
            acc[j] = mfma16(a0, b, acc[j]);
        }
    }
    const int oc = pt * 64 + w * 16 + lq * 4;
    const float4 b4 = *(const float4*)(clsb + oc);
    const int pl = w * 16 + lq * 4;
#pragma unroll
    for (int j = 0; j < 14; ++j) {
        int p = j * 16 + l15;
        if (p < 196) {
            s_pool[(pl + 0) * 200 + p] = fmaxf(acc[j][0] + b4.x, 0.f);
            s_pool[(pl + 1) * 200 + p] = fmaxf(acc[j][1] + b4.y, 0.f);
            s_pool[(pl + 2) * 200 + p] = fmaxf(acc[j][2] + b4.z, 0.f);
            s_pool[(pl + 3) * 200 + p] = fmaxf(acc[j][3] + b4.w, 0.f);
        }
    }
    __syncthreads();
    for (int i = tid; i < 64 * 49; i += 256) {
        int plx = i / 49, q = i - plx * 49;
        int py = q / 7, qx = q - py * 7;
        const float* rp = s_pool + plx * 200 + py * 28 + qx * 2;
        float m = fmaxf(fmaxf(rp[0], rp[1]), fmaxf(rp[14], rp[15]));
        act[(size_t)n * 50176 + (size_t)(pt * 64 + plx) * 49 + q] = m;
    }
}

// ---------------------------------------------------------------------------
// fc1 split-K + reduce + fc2 (fp32, unchanged from round 1).
// ---------------------------------------------------------------------------
__global__ __launch_bounds__(256) void k_fc1p(const float* __restrict__ act,
                                              const float* __restrict__ w,
                                              float* __restrict__ part)
{
    __shared__ float s_a[64 * 65];
    const int jt = blockIdx.x & 15, ks = blockIdx.x >> 4;
    const int j0 = jt * 64, k0 = ks * 3136;
    const int tid = threadIdx.x, lane = tid & 63, wave = tid >> 6;
    const int kl = tid & 63, nl = tid >> 6;
    float acc[16] = {};
    const int jbase = __builtin_amdgcn_readfirstlane(j0 + wave * 16);
    for (int kc = 0; kc < 3136; kc += 64) {
        __syncthreads();
        for (int nn = nl; nn < 64; nn += 4)
            s_a[kl * 65 + nn] = act[(size_t)nn * 50176 + k0 + kc + kl];
        __syncthreads();
        const float* wbase = w + (size_t)jbase * 50176 + k0 + kc;
#pragma unroll 4
        for (int k = 0; k < 64; ++k) {
            float a = s_a[k * 65 + lane];
#pragma unroll
            for (int jj = 0; jj < 16; ++jj)
                acc[jj] = fmaf(a, wbase[(size_t)jj * 50176 + k], acc[jj]);
        }
    }
    for (int jj = 0; jj < 16; ++jj)
        part[((size_t)ks * 1024 + jbase + jj) * 64 + lane] = acc[jj];
}

__global__ __launch_bounds__(256) void k_fc1r(const float* __restrict__ part,
                                              const float* __restrict__ b,
                                              float* __restrict__ fc1T)
{
    int i = blockIdx.x * 256 + threadIdx.x;
    if (i >= 65536) return;
    float s = 0.0f;
    for (int ks = 0; ks < 16; ++ks) s += part[(size_t)ks * 65536 + i];
    int j = i >> 6;
    fc1T[i] = fmaxf(s + b[j], 0.0f);
}

__global__ __launch_bounds__(256) void k_fc2(const float* __restrict__ fc1T,
                                             const float* __restrict__ w,
                                             const float* __restrict__ b,
                                             float* __restrict__ out)
{
    __shared__ float red[256];
    const int a_ = blockIdx.x;
    const int tid = threadIdx.x, lane = tid & 63, q = tid >> 6;
    float acc = 0.0f;
    const float* wr = w + (size_t)a_ * 1024;
    for (int k = q * 256; k < q * 256 + 256; ++k)
        acc = fmaf(fc1T[k * 64 + lane], wr[k], acc);
    red[tid] = acc;
    __syncthreads();
    if (q == 0) {
        float s = red[tid] + red[tid + 64] + red[tid + 128] + red[tid + 192] + b[a_];
        out[lane * 28 + a_] = s;
    }
}

extern "C" void kernel_launch(void* const* d_in, const int* in_sizes, int n_in,
                              void* d_out, int out_size, void* d_ws, size_t ws_size,
                              hipStream_t stream)
{
    const float* feats = (const float*)d_in[0];
    const int*   prog  = (const int*)d_in[1];
    char* ws  = (char*)d_ws;
    float* out = (float*)d_out;

    RepackArgs ra;
    ra.src[0]  = (const float*)d_in[2];   // stem_w1
    ra.src[1]  = (const float*)d_in[4];   // stem_w2
    ra.src[2]  = (const float*)d_in[6];   // att_w1
    ra.src[3]  = (const float*)d_in[8];   // att_w2
    ra.src[4]  = (const float*)d_in[12];  // rel_w1
    ra.src[5]  = (const float*)d_in[14];  // rel_w2
    ra.src[6]  = (const float*)d_in[16];  // rel_w3
    ra.src[7]  = (const float*)d_in[18];  // rel_w4
    ra.src[8]  = (const float*)d_in[20];  // rel_w5
    ra.src[9]  = (const float*)d_in[24];  // qry_w1
    ra.src[10] = (const float*)d_in[26];  // qry_w2
    ra.src[11] = (const float*)d_in[28];  // cls_w

    k_repack<<<dim3(64, 12), 256, 0, stream>>>(ra, ws);
    k_decode_init<<<256, 256, 0, stream>>>(prog, ws);

    // stem1: feats(f32) -> XA ; stem2: XA -> STEM
    k_conv_stem<<<256, 256, 0, stream>>>(feats, (const unsigned short*)(ws + B_WSTEM1),
                                         (const float*)d_in[3],
                                         (unsigned short*)(ws + B_XA), 1024, nullptr);
    k_conv_stem<<<256, 256, 0, stream>>>(nullptr, (const unsigned short*)(ws + B_WSTEM2),
                                         (const float*)d_in[5],
                                         (unsigned short*)(ws + B_STEM), 128,
                                         (const unsigned short*)(ws + B_XA));

    RArgs ga;
    ga.ws = ws;
    ga.mbias[0] = (const float*)d_in[7];   // att_b1
    ga.mbias[1] = (const float*)d_in[9];   // att_b2
    ga.mbias[2] = (const float*)d_in[13];  // rel_b1
    ga.mbias[3] = (const float*)d_in[15];  // rel_b2
    ga.mbias[4] = (const float*)d_in[17];  // rel_b3
    ga.mbias[5] = (const float*)d_in[19];  // rel_b4
    ga.mbias[6] = (const float*)d_in[21];  // rel_b5
    ga.mbias[7] = (const float*)d_in[25];  // qry_b1
    ga.mbias[8] = (const float*)d_in[27];  // qry_b2
    ga.w1x1[0]  = (const float*)d_in[10];  // att_w3
    ga.w1x1[1]  = (const float*)d_in[22];  // rel_w6
    ga.b1x1[0]  = (const float*)d_in[11];  // att_b3
    ga.b1x1[1]  = (const float*)d_in[23];  // rel_b6

    for (int r = 0; r < NROUNDS; ++r)
        k_round<<<256, 256, 0, stream>>>(ga, r);

    k_cls_pool<<<1024, 256, 0, stream>>>((const unsigned short*)(ws + B_FEAT),
                                         (const unsigned short*)(ws + B_WCLS),
                                         (const float*)d_in[29], (float*)(ws + B_ACT));
    k_fc1p<<<256, 256, 0, stream>>>((const float*)(ws + B_ACT), (const float*)d_in[30],
                                    (float*)(ws + B_FC1P));
    k_fc1r<<<256, 256, 0, stream>>>((const float*)(ws + B_FC1P), (const float*)d_in[31],
                                    (float*)(ws + B_FC1T));
    k_fc2<<<28, 256, 0, stream>>>((const float*)(ws + B_FC1T), (const float*)d_in[32],
                                  (const float*)d_in[33], out);
}

// Round 3
// 726.379 us; speedup vs baseline: 7.0269x; 1.5890x over previous
//
#include <hip/hip_runtime.h>
#include <math.h>

// ---------------------------------------------------------------------------
// TbDNet forward, round 3: conv stack on bf16 MFMA (unchanged), fc1 rebuilt as
// streaming bf16-MFMA skinny GEMM (W read once, coalesced vector loads).
// ---------------------------------------------------------------------------

typedef __attribute__((ext_vector_type(8)))  short   short8;
typedef __attribute__((ext_vector_type(8)))  __bf16  bf16x8;
typedef __attribute__((ext_vector_type(4)))  float   f32x4;

#define NROUNDS 15
#define NKS 32          // fc1 K-splits (KC = 50176/32 = 1568)

// byte offsets in ws
#define B_WSTEM1 0UL                 // bf16 [9][128][1024]
#define B_WSTEM2 2359296UL           // bf16 [9][128][128]
#define B_WMOD   2654208UL           // 9 x bf16 [9][128][128]
#define B_WCLS   5308416UL           // bf16 [1024][128]
#define B_STEM   5570560UL           // bf16 [64][196][128]
#define B_XA     8781824UL
#define B_XB     11993088UL
#define B_FEAT   15204352UL
#define B_ATTN   18415616UL          // f32 [64][196]
#define B_SAVED  18465792UL
#define B_SCHED  18515968UL          // int [64][NROUNDS]
#define B_ACTB   18520064UL          // bf16 [50176/8][64][8] = 6422528 B
#define B_FC1T   24942592UL          // f32 [1024][64]
#define B_FC1P   B_XA                // overlay: f32 [NKS][1024][64] = 8388608 B (XA/XB dead)

__device__ __forceinline__ unsigned short f2bf(float f) {
    unsigned int b = __float_as_uint(f);
    b += 0x7fffu + ((b >> 16) & 1u);          // RNE
    return (unsigned short)(b >> 16);
}
__device__ __forceinline__ float bf2f(unsigned short u) {
    return __uint_as_float(((unsigned int)u) << 16);
}
__device__ __forceinline__ f32x4 mfma16(bf16x8 a, bf16x8 b, f32x4 c) {
    return __builtin_amdgcn_mfma_f32_16x16x32_bf16(a, b, c, 0, 0, 0);
}

// ---------------------------------------------------------------------------
// Weight repack: conv sets -> [tap][oc][ic] bf16; cls_w -> straight bf16.
// ---------------------------------------------------------------------------
struct RepackArgs { const float* src[12]; };

__global__ __launch_bounds__(256) void k_repack(RepackArgs a, char* ws)
{
    const int y = blockIdx.y;
    const float* __restrict__ src = a.src[y];
    int gid = blockIdx.x * 256 + threadIdx.x;
    int gsz = gridDim.x * 256;
    if (y == 11) {
        unsigned short* dst = (unsigned short*)(ws + B_WCLS);
        for (int i = gid; i < 131072; i += gsz) dst[i] = f2bf(src[i]);
    } else {
        const int IC = (y == 0) ? 1024 : 128;
        const int lg = (y == 0) ? 10 : 7;
        unsigned short* dst = (unsigned short*)(ws + ((y == 0) ? B_WSTEM1
                                    : (y == 1) ? B_WSTEM2
                                    : B_WMOD + (size_t)(y - 2) * 294912));
        const int total = 9 << (lg + 7);
        for (int i = gid; i < total; i += gsz) {
            int ic = i & (IC - 1);
            int oc = (i >> lg) & 127;
            int t  = i >> (lg + 7);
            dst[i] = f2bf(src[((size_t)oc * IC + ic) * 9 + t]);
        }
    }
}

// ---------------------------------------------------------------------------
// Program decode + state init.
// ---------------------------------------------------------------------------
__global__ __launch_bounds__(256) void k_decode_init(const int* __restrict__ prog, char* ws)
{
    int gid = blockIdx.x * 256 + threadIdx.x;
    int gsz = gridDim.x * 256;
    float* attn  = (float*)(ws + B_ATTN);
    float* saved = (float*)(ws + B_SAVED);
    for (int i = gid; i < 64 * 196; i += gsz) { attn[i] = 1.0f; saved[i] = 1.0f; }
    unsigned int* fz = (unsigned int*)(ws + B_FEAT);
    for (int i = gid; i < 64 * 25088 / 2; i += gsz) fz[i] = 0u;
    if (gid < 64) {
        int n = gid;
        int ent[NROUNDS];
        for (int r = 0; r < NROUNDS; ++r) ent[r] = 0;
        int rc = 0;
#define ENC(op,wv,dl,g,s,d) ((op)|((wv)<<4)|((dl)<<8)|((g)<<12)|((s)<<13)|((d)<<15))
#define EMIT(v) do { if (rc < NROUNDS) ent[rc++] = (v); } while (0)
        for (int j = 7; j >= 0; --j) {
            int t = prog[n * 8 + j];
            switch (t) {
                case 3: EMIT(ENC(1,0,0,0,0,0)); break;  // SCENE
                case 4: EMIT(ENC(2,0,0,0,0,0)); break;  // INTERSECT
                case 5:                                  // FILT
                    EMIT(ENC(3,0,1,1,3,0));
                    EMIT(ENC(3,1,1,0,0,1));
                    EMIT(ENC(4,0,0,0,1,0));
                    break;
                case 6:                                  // RELATE
                    EMIT(ENC(3,2,1,1,3,0));
                    EMIT(ENC(3,3,2,0,0,1));
                    EMIT(ENC(3,4,4,0,1,0));
                    EMIT(ENC(3,5,8,0,0,1));
                    EMIT(ENC(3,6,1,0,1,0));
                    EMIT(ENC(4,1,0,0,0,0));
                    break;
                case 7:                                  // QUERY
                    EMIT(ENC(3,7,1,1,3,0));
                    EMIT(ENC(3,8,1,0,0,2));
                    break;
                default: break;
            }
        }
#undef EMIT
#undef ENC
        int* sched = (int*)(ws + B_SCHED);
        for (int r = 0; r < NROUNDS; ++r) sched[n * NROUNDS + r] = ent[r];
    }
}

// ---------------------------------------------------------------------------
// MFMA 3x3 dilated conv core (unchanged from round 2).
// ---------------------------------------------------------------------------
__device__ void conv_mfma_core(const unsigned short* __restrict__ srcB,
                               const float*  __restrict__ srcF,
                               const float*  __restrict__ gate,
                               const unsigned short* __restrict__ wrep,
                               const float*  __restrict__ bias,
                               unsigned short* __restrict__ dst,
                               int ICtot, int dil, int och, int pxh,
                               unsigned short* s_img)
{
    const int tid  = threadIdx.x, lane = tid & 63;
    const int w    = tid >> 6, wm = w & 1, wn = w >> 1;
    const int l15  = lane & 15, lq = lane >> 4;

    if (tid < 68) ((unsigned int*)s_img)[196 * 68 + tid] = 0u;   // zero page row

    int pglob[4], pbyt[4], pyv[4], pxv[4];
#pragma unroll
    for (int j = 0; j < 4; ++j) {
        int nt = wn + 2 * j;
        int p  = (pxh * 7 + nt) * 16 + l15;
        pglob[j] = p;
        int py = p / 14;
        pyv[j] = (p < 196) ? py : 10000;
        pxv[j] = p - py * 14;
        pbyt[j] = p * 272 + lq * 16;
    }
    const int zaddr = 196 * 272 + lq * 16;
    const int nNT = (wn == 0) ? 4 : 3;

    f32x4 acc[2][4];
#pragma unroll
    for (int m = 0; m < 2; ++m)
#pragma unroll
        for (int j = 0; j < 4; ++j) acc[m][j] = (f32x4){0.f, 0.f, 0.f, 0.f};

    const unsigned short* wlane = wrep + (size_t)(och * 64 + wm * 32 + l15) * ICtot + lq * 8;
    const int nslab = ICtot >> 7;

    for (int slab = 0; slab < nslab; ++slab) {
        if (slab) __syncthreads();
        if (srcF) {                                   // fp32 C-major source (stem1)
            const float* sf = srcF + slab * 128 * 196;
            for (int i = tid; i < 128 * 196; i += 256) {
                int ic = i / 196, p = i - ic * 196;
                s_img[p * 136 + ic] = f2bf(sf[i]);
            }
        } else if (gate) {                            // bf16 source, gated
            for (int i = tid; i < 196 * 16; i += 256) {
                int p = i >> 4, c8 = (i & 15) * 8;
                short8 v = *(const short8*)(srcB + p * 128 + c8);
                float g = gate[p];
                short8 ov;
#pragma unroll
                for (int e = 0; e < 8; ++e)
                    ov[e] = (short)f2bf(bf2f((unsigned short)v[e]) * g);
                *(short8*)(s_img + p * 136 + c8) = ov;
            }
        } else {                                      // bf16 source, plain copy
            for (int i = tid; i < 196 * 16; i += 256) {
                int p = i >> 4, c8 = (i & 15) * 8;
                *(short8*)(s_img + p * 136 + c8) = *(const short8*)(srcB + p * 128 + c8);
            }
        }
        __syncthreads();

        const unsigned short* wslab = wlane + slab * 128;
#pragma unroll
        for (int t = 0; t < 9; ++t) {
            const int dy = (t / 3 - 1) * dil, dx = (t % 3 - 1) * dil;
            int baddr[4];
#pragma unroll
            for (int j = 0; j < 4; ++j) {
                int yy = pyv[j] + dy, xx = pxv[j] + dx;
                bool ok = ((unsigned)yy < 14u) && ((unsigned)xx < 14u);
                baddr[j] = ok ? (pbyt[j] + (dy * 14 + dx) * 272) : zaddr;
            }
            const unsigned short* wt = wslab + (size_t)(t * 128) * ICtot;
#pragma unroll
            for (int kc = 0; kc < 4; ++kc) {
                bf16x8 a0 = *(const bf16x8*)(wt + kc * 32);
                bf16x8 a1 = *(const bf16x8*)(wt + (size_t)16 * ICtot + kc * 32);
#pragma unroll
                for (int j = 0; j < 4; ++j) {
                    if (j < nNT) {
                        bf16x8 b = *(const bf16x8*)((const char*)s_img + baddr[j] + kc * 64);
                        acc[0][j] = mfma16(a0, b, acc[0][j]);
                        acc[1][j] = mfma16(a1, b, acc[1][j]);
                    }
                }
            }
        }
    }

    // epilogue: bias + relu -> bf16 [196][128]
#pragma unroll
    for (int m = 0; m < 2; ++m) {
        const int oc = och * 64 + wm * 32 + m * 16 + lq * 4;
        const float4 b4 = *(const float4*)(bias + oc);
#pragma unroll
        for (int j = 0; j < 4; ++j) {
            if (j < nNT) {
                int p = pglob[j];
                if (p < 196) {
                    float v0 = fmaxf(acc[m][j][0] + b4.x, 0.f);
                    float v1 = fmaxf(acc[m][j][1] + b4.y, 0.f);
                    float v2 = fmaxf(acc[m][j][2] + b4.z, 0.f);
                    float v3 = fmaxf(acc[m][j][3] + b4.w, 0.f);
                    unsigned int lo = (unsigned int)f2bf(v0) | ((unsigned int)f2bf(v1) << 16);
                    unsigned int hi = (unsigned int)f2bf(v2) | ((unsigned int)f2bf(v3) << 16);
                    uint2 pk; pk.x = lo; pk.y = hi;
                    *(uint2*)(dst + p * 128 + oc) = pk;
                }
            }
        }
    }
}

__global__ __launch_bounds__(256) void k_conv_stem(const float* __restrict__ featsF,
                                                   const unsigned short* __restrict__ wrep,
                                                   const float* __restrict__ bias,
                                                   unsigned short* __restrict__ dstall,
                                                   int ICtot,
                                                   const unsigned short* __restrict__ srcBall)
{
    __shared__ unsigned short s_img[197 * 136];
    const int n = blockIdx.x >> 2, och = (blockIdx.x >> 1) & 1, pxh = blockIdx.x & 1;
    if (ICtot == 1024)
        conv_mfma_core(nullptr, featsF + (size_t)n * 1024 * 196, nullptr, wrep, bias,
                       dstall + (size_t)n * 25088, 1024, 1, och, pxh, s_img);
    else
        conv_mfma_core(srcBall + (size_t)n * 25088, nullptr, nullptr, wrep, bias,
                       dstall + (size_t)n * 25088, 128, 1, och, pxh, s_img);
}

// ---------------------------------------------------------------------------
// Module interpreter round.
// ---------------------------------------------------------------------------
struct RArgs {
    char* ws;
    const float* mbias[9];
    const float* w1x1[2];
    const float* b1x1[2];
};

__global__ __launch_bounds__(256) void k_round(RArgs a, int r)
{
    __shared__ unsigned short s_img[197 * 136];
    const int bx = blockIdx.x;
    const int n = bx >> 2, och = (bx >> 1) & 1, pxh = bx & 1;
    char* ws = a.ws;
    const int* sched = (const int*)(ws + B_SCHED);
    const int e = sched[n * NROUNDS + r];
    const int op = e & 15;
    if (op == 0) return;
    float* attn  = (float*)(ws + B_ATTN)  + n * 196;
    float* saved = (float*)(ws + B_SAVED) + n * 196;
    if (op == 1 || op == 2) {
        if ((bx & 3) == 0 && threadIdx.x < 196) {
            int p = threadIdx.x;
            if (op == 1) { saved[p] = attn[p]; attn[p] = 1.0f; }
            else         attn[p] = fminf(attn[p], saved[p]);
        }
        return;
    }
    const int wset = (e >> 4) & 15, dil = (e >> 8) & 15, gatef = (e >> 12) & 1;
    const int srcid = (e >> 13) & 3, dstid = (e >> 15) & 3;
    const unsigned short* src = (const unsigned short*)(ws +
            (srcid == 3 ? B_STEM : srcid == 1 ? B_XB : B_XA)) + (size_t)n * 25088;
    if (op == 4) {                                  // conv1x1 + sigmoid -> attn
        if ((bx & 3) == 0 && threadIdx.x < 196) {
            int p = threadIdx.x;
            const float* wv = a.w1x1[wset];
            float acc = a.b1x1[wset][0];
            const unsigned short* row = src + p * 128;
#pragma unroll 8
            for (int ic = 0; ic < 128; ++ic) acc += bf2f(row[ic]) * wv[ic];
            attn[p] = 1.0f / (1.0f + __expf(-acc));
        }
        return;
    }
    unsigned short* dst = (unsigned short*)(ws +
            (dstid == 2 ? B_FEAT : dstid == 1 ? B_XB : B_XA)) + (size_t)n * 25088;
    const unsigned short* wrep = (const unsigned short*)(ws + B_WMOD) + (size_t)wset * 9 * 128 * 128;
    conv_mfma_core(src, nullptr, gatef ? attn : nullptr, wrep, a.mbias[wset], dst,
                   128, dil, och, pxh, s_img);
}

// ---------------------------------------------------------------------------
// cls 1x1 conv (128->1024, MFMA) + bias + relu + 2x2 maxpool -> actB bf16
// in fc1 B-fragment layout [k/8][n=64][8].
// ---------------------------------------------------------------------------
__global__ __launch_bounds__(256) void k_cls_pool(const unsigned short* __restrict__ featall,
                                                  const unsigned short* __restrict__ clsw,
                                                  const float* __restrict__ clsb,
                                                  unsigned short* __restrict__ actB)
{
    __shared__ char smem[197 * 272 + 64 * 200 * 4];
    unsigned short* s_img = (unsigned short*)smem;
    float* s_pool = (float*)(smem + 197 * 272);
    const int n = blockIdx.x >> 4, pt = blockIdx.x & 15;
    const int tid = threadIdx.x, lane = tid & 63, w = tid >> 6;
    const int l15 = lane & 15, lq = lane >> 4;
    const unsigned short* feat = featall + (size_t)n * 25088;

    if (tid < 68) ((unsigned int*)s_img)[196 * 68 + tid] = 0u;
    for (int i = tid; i < 196 * 16; i += 256) {
        int p = i >> 4, c8 = (i & 15) * 8;
        *(short8*)(s_img + p * 136 + c8) = *(const short8*)(feat + p * 128 + c8);
    }
    f32x4 acc[14];
#pragma unroll
    for (int j = 0; j < 14; ++j) acc[j] = (f32x4){0.f, 0.f, 0.f, 0.f};
    __syncthreads();

    const unsigned short* wl = clsw + (size_t)(pt * 64 + w * 16 + l15) * 128 + lq * 8;
#pragma unroll
    for (int kc = 0; kc < 4; ++kc) {
        bf16x8 a0 = *(const bf16x8*)(wl + kc * 32);
#pragma unroll
        for (int j = 0; j < 14; ++j) {
            int p = j * 16 + l15;
            int ba = (p < 196) ? (p * 272 + lq * 16 + kc * 64) : (196 * 272 + lq * 16);
            bf16x8 b = *(const bf16x8*)((const char*)s_img + ba);
            acc[j] = mfma16(a0, b, acc[j]);
        }
    }
    const int oc = pt * 64 + w * 16 + lq * 4;
    const float4 b4 = *(const float4*)(clsb + oc);
    const int pl = w * 16 + lq * 4;
#pragma unroll
    for (int j = 0; j < 14; ++j) {
        int p = j * 16 + l15;
        if (p < 196) {
            s_pool[(pl + 0) * 200 + p] = fmaxf(acc[j][0] + b4.x, 0.f);
            s_pool[(pl + 1) * 200 + p] = fmaxf(acc[j][1] + b4.y, 0.f);
            s_pool[(pl + 2) * 200 + p] = fmaxf(acc[j][2] + b4.z, 0.f);
            s_pool[(pl + 3) * 200 + p] = fmaxf(acc[j][3] + b4.w, 0.f);
        }
    }
    __syncthreads();
    for (int i = tid; i < 64 * 49; i += 256) {
        int plx = i / 49, q = i - plx * 49;
        int py = q / 7, qx = q - py * 7;
        const float* rp = s_pool + plx * 200 + py * 28 + qx * 2;
        float m = fmaxf(fmaxf(rp[0], rp[1]), fmaxf(rp[14], rp[15]));
        int k = (pt * 64 + plx) * 49 + q;
        actB[(size_t)(k >> 3) * 512 + n * 8 + (k & 7)] = f2bf(m);
    }
}

// ---------------------------------------------------------------------------
// fc1 partial GEMM: C[1024 j][64 n] += W[j][k] * actB[k][n], bf16 MFMA.
// Grid: blockIdx = ks*16 + jt. Block: 4 waves, wave w -> j rows jt*64+w*16+..
// Each lane streams W fp32 (coalesced 128B/row runs), converts to bf16.
// ---------------------------------------------------------------------------
__global__ __launch_bounds__(256) void k_fc1p(const unsigned short* __restrict__ actB,
                                              const float* __restrict__ w,
                                              float* __restrict__ part)
{
    const int jt = blockIdx.x & 15, ks = blockIdx.x >> 4;
    const int tid = threadIdx.x, lane = tid & 63, wv = tid >> 6;
    const int l15 = lane & 15, lq = lane >> 4;
    const int KC = 50176 / NKS;                 // 1568
    const int k0 = ks * KC;
    const int j = jt * 64 + wv * 16 + l15;      // A-fragment row for this lane

    f32x4 acc[4];
#pragma unroll
    for (int t = 0; t < 4; ++t) acc[t] = (f32x4){0.f, 0.f, 0.f, 0.f};

    const float* wrow = w + (size_t)j * 50176 + k0 + lq * 8;
    const unsigned short* bbase = actB + (size_t)(k0 >> 3) * 512;

    for (int kc = 0; kc < KC; kc += 32) {
        float4 wa = *(const float4*)(wrow + kc);
        float4 wb = *(const float4*)(wrow + kc + 4);
        bf16x8 a;
        a[0] = (__bf16)wa.x; a[1] = (__bf16)wa.y; a[2] = (__bf16)wa.z; a[3] = (__bf16)wa.w;
        a[4] = (__bf16)wb.x; a[5] = (__bf16)wb.y; a[6] = (__bf16)wb.z; a[7] = (__bf16)wb.w;
        const unsigned short* bk = bbase + (size_t)((kc >> 3) + lq) * 512 + l15 * 8;
#pragma unroll
        for (int t = 0; t < 4; ++t) {
            bf16x8 b = *(const bf16x8*)(bk + t * 128);
            acc[t] = mfma16(a, b, acc[t]);
        }
    }

    // C layout per m89: row = lq*4 + r (j-local), col = l15 (n)
    float* pbase = part + ((size_t)ks * 1024 + jt * 64 + wv * 16 + lq * 4) * 64 + l15;
#pragma unroll
    for (int t = 0; t < 4; ++t)
#pragma unroll
        for (int r = 0; r < 4; ++r)
            pbase[(size_t)r * 64 + t * 16] = acc[t][r];
}

__global__ __launch_bounds__(256) void k_fc1r(const float* __restrict__ part,
                                              const float* __restrict__ b,
                                              float* __restrict__ fc1T)
{
    int i = blockIdx.x * 256 + threadIdx.x;
    if (i >= 65536) return;
    float s = 0.0f;
    for (int ks = 0; ks < NKS; ++ks) s += part[(size_t)ks * 65536 + i];
    int j = i >> 6;
    fc1T[i] = fmaxf(s + b[j], 0.0f);
}

__global__ __launch_bounds__(256) void k_fc2(const float* __restrict__ fc1T,
                                             const float* __restrict__ w,
                                             const float* __restrict__ b,
                                             float* __restrict__ out)
{
    __shared__ float red[256];
    const int a_ = blockIdx.x;
    const int tid = threadIdx.x, lane = tid & 63, q = tid >> 6;
    float acc = 0.0f;
    const float* wr = w + (size_t)a_ * 1024;
    for (int k = q * 256; k < q * 256 + 256; ++k)
        acc = fmaf(fc1T[k * 64 + lane], wr[k], acc);
    red[tid] = acc;
    __syncthreads();
    if (q == 0) {
        float s = red[tid] + red[tid + 64] + red[tid + 128] + red[tid + 192] + b[a_];
        out[lane * 28 + a_] = s;
    }
}

extern "C" void kernel_launch(void* const* d_in, const int* in_sizes, int n_in,
                              void* d_out, int out_size, void* d_ws, size_t ws_size,
                              hipStream_t stream)
{
    const float* feats = (const float*)d_in[0];
    const int*   prog  = (const int*)d_in[1];
    char* ws  = (char*)d_ws;
    float* out = (float*)d_out;

    RepackArgs ra;
    ra.src[0]  = (const float*)d_in[2];   // stem_w1
    ra.src[1]  = (const float*)d_in[4];   // stem_w2
    ra.src[2]  = (const float*)d_in[6];   // att_w1
    ra.src[3]  = (const float*)d_in[8];   // att_w2
    ra.src[4]  = (const float*)d_in[12];  // rel_w1
    ra.src[5]  = (const float*)d_in[14];  // rel_w2
    ra.src[6]  = (const float*)d_in[16];  // rel_w3
    ra.src[7]  = (const float*)d_in[18];  // rel_w4
    ra.src[8]  = (const float*)d_in[20];  // rel_w5
    ra.src[9]  = (const float*)d_in[24];  // qry_w1
    ra.src[10] = (const float*)d_in[26];  // qry_w2
    ra.src[11] = (const float*)d_in[28];  // cls_w

    k_repack<<<dim3(64, 12), 256, 0, stream>>>(ra, ws);
    k_decode_init<<<256, 256, 0, stream>>>(prog, ws);

    // stem1: feats(f32) -> XA ; stem2: XA -> STEM
    k_conv_stem<<<256, 256, 0, stream>>>(feats, (const unsigned short*)(ws + B_WSTEM1),
                                         (const float*)d_in[3],
                                         (unsigned short*)(ws + B_XA), 1024, nullptr);
    k_conv_stem<<<256, 256, 0, stream>>>(nullptr, (const unsigned short*)(ws + B_WSTEM2),
                                         (const float*)d_in[5],
                                         (unsigned short*)(ws + B_STEM), 128,
                                         (const unsigned short*)(ws + B_XA));

    RArgs ga;
    ga.ws = ws;
    ga.mbias[0] = (const float*)d_in[7];   // att_b1
    ga.mbias[1] = (const float*)d_in[9];   // att_b2
    ga.mbias[2] = (const float*)d_in[13];  // rel_b1
    ga.mbias[3] = (const float*)d_in[15];  // rel_b2
    ga.mbias[4] = (const float*)d_in[17];  // rel_b3
    ga.mbias[5] = (const float*)d_in[19];  // rel_b4
    ga.mbias[6] = (const float*)d_in[21];  // rel_b5
    ga.mbias[7] = (const float*)d_in[25];  // qry_b1
    ga.mbias[8] = (const float*)d_in[27];  // qry_b2
    ga.w1x1[0]  = (const float*)d_in[10];  // att_w3
    ga.w1x1[1]  = (const float*)d_in[22];  // rel_w6
    ga.b1x1[0]  = (const float*)d_in[11];  // att_b3
    ga.b1x1[1]  = (const float*)d_in[23];  // rel_b6

    for (int r = 0; r < NROUNDS; ++r)
        k_round<<<256, 256, 0, stream>>>(ga, r);

    k_cls_pool<<<1024, 256, 0, stream>>>((const unsigned short*)(ws + B_FEAT),
                                         (const unsigned short*)(ws + B_WCLS),
                                         (const float*)d_in[29],
                                         (unsigned short*)(ws + B_ACTB));
    k_fc1p<<<512, 256, 0, stream>>>((const unsigned short*)(ws + B_ACTB),
                                    (const float*)d_in[30], (float*)(ws + B_FC1P));
    k_fc1r<<<256, 256, 0, stream>>>((const float*)(ws + B_FC1P), (const float*)d_in[31],
                                    (float*)(ws + B_FC1T));
    k_fc2<<<28, 256, 0, stream>>>((const float*)(ws + B_FC1T), (const float*)d_in[32],
                                  (const float*)d_in[33], out);
}

// Round 4
// 598.267 us; speedup vs baseline: 8.5317x; 1.2141x over previous
//
#include <hip/hip_runtime.h>
#include <math.h>

// ---------------------------------------------------------------------------
// TbDNet forward, round 4: stem1 K-split with bf16 partials + swizzled staging;
// fc1 rebuilt with 64B-contiguous W streaming and k-permuted actB.
// ---------------------------------------------------------------------------

typedef __attribute__((ext_vector_type(8)))  short   short8;
typedef __attribute__((ext_vector_type(8)))  __bf16  bf16x8;
typedef __attribute__((ext_vector_type(4)))  float   f32x4;

#define NROUNDS 15
#define NKS 49          // fc1 K-splits (KC = 50176/49 = 1024)

// byte offsets in ws
#define B_WSTEM1 0UL                 // bf16 [9][128][1024]
#define B_WSTEM2 2359296UL           // bf16 [9][128][128]
#define B_WMOD   2654208UL           // 9 x bf16 [9][128][128]
#define B_WCLS   5308416UL           // bf16 [1024][128]
#define B_STEM   5570560UL           // bf16 [64][196][128]
#define B_XA     8781824UL
#define B_XB     11993088UL
#define B_FEAT   15204352UL
#define B_ATTN   18415616UL          // f32 [64][196]
#define B_SAVED  18465792UL
#define B_SCHED  18515968UL          // int [64][NROUNDS]
#define B_ACTB   18520064UL          // bf16 permuted fc1-B, 6422528 B
#define B_FC1T   24942592UL          // f32 [1024][64]
// overlays:
#define B_S1P    B_XB                // stem1 partials bf16 [4][64][196][128] = 12845056 B
#define B_FC1P   B_STEM              // fc1 partials f32 [49][1024][64] = 12845056 B (ends at B_ATTN)

__device__ __forceinline__ unsigned short f2bf(float f) {
    unsigned int b = __float_as_uint(f);
    b += 0x7fffu + ((b >> 16) & 1u);          // RNE
    return (unsigned short)(b >> 16);
}
__device__ __forceinline__ float bf2f(unsigned short u) {
    return __uint_as_float(((unsigned int)u) << 16);
}
__device__ __forceinline__ f32x4 mfma16(bf16x8 a, bf16x8 b, f32x4 c) {
    return __builtin_amdgcn_mfma_f32_16x16x32_bf16(a, b, c, 0, 0, 0);
}

// ---------------------------------------------------------------------------
// Weight repack: conv sets -> [tap][oc][ic] bf16; cls_w -> straight bf16.
// ---------------------------------------------------------------------------
struct RepackArgs { const float* src[12]; };

__global__ __launch_bounds__(256) void k_repack(RepackArgs a, char* ws)
{
    const int y = blockIdx.y;
    const float* __restrict__ src = a.src[y];
    int gid = blockIdx.x * 256 + threadIdx.x;
    int gsz = gridDim.x * 256;
    if (y == 11) {
        unsigned short* dst = (unsigned short*)(ws + B_WCLS);
        for (int i = gid; i < 131072; i += gsz) dst[i] = f2bf(src[i]);
    } else {
        const int IC = (y == 0) ? 1024 : 128;
        const int lg = (y == 0) ? 10 : 7;
        unsigned short* dst = (unsigned short*)(ws + ((y == 0) ? B_WSTEM1
                                    : (y == 1) ? B_WSTEM2
                                    : B_WMOD + (size_t)(y - 2) * 294912));
        const int total = 9 << (lg + 7);
        for (int i = gid; i < total; i += gsz) {
            int ic = i & (IC - 1);
            int oc = (i >> lg) & 127;
            int t  = i >> (lg + 7);
            dst[i] = f2bf(src[((size_t)oc * IC + ic) * 9 + t]);
        }
    }
}

// ---------------------------------------------------------------------------
// Program decode + state init (also zeroes FEAT; run AFTER stem1 reduce since
// FEAT region overlays stem1 partials).
// ---------------------------------------------------------------------------
__global__ __launch_bounds__(256) void k_decode_init(const int* __restrict__ prog, char* ws)
{
    int gid = blockIdx.x * 256 + threadIdx.x;
    int gsz = gridDim.x * 256;
    float* attn  = (float*)(ws + B_ATTN);
    float* saved = (float*)(ws + B_SAVED);
    for (int i = gid; i < 64 * 196; i += gsz) { attn[i] = 1.0f; saved[i] = 1.0f; }
    unsigned int* fz = (unsigned int*)(ws + B_FEAT);
    for (int i = gid; i < 64 * 25088 / 2; i += gsz) fz[i] = 0u;
    if (gid < 64) {
        int n = gid;
        int ent[NROUNDS];
        for (int r = 0; r < NROUNDS; ++r) ent[r] = 0;
        int rc = 0;
#define ENC(op,wv,dl,g,s,d) ((op)|((wv)<<4)|((dl)<<8)|((g)<<12)|((s)<<13)|((d)<<15))
#define EMIT(v) do { if (rc < NROUNDS) ent[rc++] = (v); } while (0)
        for (int j = 7; j >= 0; --j) {
            int t = prog[n * 8 + j];
            switch (t) {
                case 3: EMIT(ENC(1,0,0,0,0,0)); break;  // SCENE
                case 4: EMIT(ENC(2,0,0,0,0,0)); break;  // INTERSECT
                case 5:                                  // FILT
                    EMIT(ENC(3,0,1,1,3,0));
                    EMIT(ENC(3,1,1,0,0,1));
                    EMIT(ENC(4,0,0,0,1,0));
                    break;
                case 6:                                  // RELATE
                    EMIT(ENC(3,2,1,1,3,0));
                    EMIT(ENC(3,3,2,0,0,1));
                    EMIT(ENC(3,4,4,0,1,0));
                    EMIT(ENC(3,5,8,0,0,1));
                    EMIT(ENC(3,6,1,0,1,0));
                    EMIT(ENC(4,1,0,0,0,0));
                    break;
                case 7:                                  // QUERY
                    EMIT(ENC(3,7,1,1,3,0));
                    EMIT(ENC(3,8,1,0,0,2));
                    break;
                default: break;
            }
        }
#undef EMIT
#undef ENC
        int* sched = (int*)(ws + B_SCHED);
        for (int r = 0; r < NROUNDS; ++r) sched[n * NROUNDS + r] = ent[r];
    }
}

// ---------------------------------------------------------------------------
// stem1 partial conv: block = (n, ks 0..3, och 0..1, pxh 0..1). Each block
// covers ic [ks*256, ks*256+256) as 2 slabs of 128, writes bf16 partials.
// LDS image: [197 rows][17 chunks of 16B], chunk XOR-swizzled by (p&15).
// ---------------------------------------------------------------------------
__global__ __launch_bounds__(256) void k_stem1p(const float* __restrict__ feats,
                                                const unsigned short* __restrict__ wrep,
                                                char* ws)
{
    __shared__ unsigned short s_img[197 * 136];
    const int bx = blockIdx.x;
    const int n = bx >> 4, ks = (bx >> 2) & 3, och = (bx >> 1) & 1, pxh = bx & 1;
    const int tid = threadIdx.x, lane = tid & 63;
    const int w = tid >> 6, wm = w & 1, wn = w >> 1;
    const int l15 = lane & 15, lq = lane >> 4;

    if (tid < 68) ((unsigned int*)s_img)[196 * 68 + tid] = 0u;   // zero row

    int pglob[4], pbyt[4], swz[4];
#pragma unroll
    for (int j = 0; j < 4; ++j) {
        int nt = wn + 2 * j;
        int p  = (pxh * 7 + nt) * 16 + l15;
        pglob[j] = p;
        pbyt[j] = p * 272;
        swz[j] = p & 15;
    }
    const int nNT = (wn == 0) ? 4 : 3;

    f32x4 acc[2][4];
#pragma unroll
    for (int m = 0; m < 2; ++m)
#pragma unroll
        for (int j = 0; j < 4; ++j) acc[m][j] = (f32x4){0.f, 0.f, 0.f, 0.f};

    for (int slab = 0; slab < 2; ++slab) {
        if (slab) __syncthreads();
        // stage fp32 slab [128 ic][196 px] -> swizzled bf16 LDS [p][ic]
        const float* sf = feats + ((size_t)n * 1024 + ks * 256 + slab * 128) * 196;
        for (int i = tid; i < 128 * 49; i += 256) {
            int ic = i / 49, q = i - ic * 49;
            float4 v = *(const float4*)(sf + ic * 196 + q * 4);
            int c = ic >> 3, e2 = (ic & 7) * 2;
#pragma unroll
            for (int e = 0; e < 4; ++e) {
                int p = q * 4 + e;
                int byte = p * 272 + ((c ^ (p & 15)) << 4) + e2;
                s_img[byte >> 1] = f2bf(((const float*)&v)[e]);
            }
        }
        __syncthreads();

        const int icb = ks * 256 + slab * 128;
#pragma unroll
        for (int t = 0; t < 9; ++t) {
            const int dy = t / 3 - 1, dx = t % 3 - 1;
            int baddr[4], bswz[4];
#pragma unroll
            for (int j = 0; j < 4; ++j) {
                int p = pglob[j];
                int py = (p < 196) ? (p / 14) : 1000;
                int px = p - py * 14;
                int yy = py + dy, xx = px + dx;
                bool ok = ((unsigned)yy < 14u) && ((unsigned)xx < 14u);
                int pp = p + dy * 14 + dx;
                baddr[j] = ok ? pp * 272 : 196 * 272;
                bswz[j]  = ok ? (pp & 15) : 0;
            }
#pragma unroll
            for (int kc = 0; kc < 4; ++kc) {
                const unsigned short* wt = wrep +
                    ((size_t)(t * 128 + och * 64 + wm * 32 + l15) * 1024 + icb + kc * 32 + lq * 8);
                bf16x8 a0 = *(const bf16x8*)(wt);
                bf16x8 a1 = *(const bf16x8*)(wt + 16 * 1024);
                const int cc = kc * 4 + lq;
#pragma unroll
                for (int j = 0; j < 4; ++j) {
                    if (j < nNT) {
                        bf16x8 b = *(const bf16x8*)((const char*)s_img +
                                     baddr[j] + ((cc ^ bswz[j]) << 4));
                        acc[0][j] = mfma16(a0, b, acc[0][j]);
                        acc[1][j] = mfma16(a1, b, acc[1][j]);
                    }
                }
            }
        }
    }

    // write bf16 partials: part[ks][n][p][oc]
    unsigned short* part = (unsigned short*)(ws + B_S1P);
#pragma unroll
    for (int m = 0; m < 2; ++m) {
        const int oc = och * 64 + wm * 32 + m * 16 + lq * 4;
#pragma unroll
        for (int j = 0; j < 4; ++j) {
            if (j < nNT) {
                int p = pglob[j];
                if (p < 196) {
                    unsigned int lo = (unsigned int)f2bf(acc[m][j][0]) |
                                      ((unsigned int)f2bf(acc[m][j][1]) << 16);
                    unsigned int hi = (unsigned int)f2bf(acc[m][j][2]) |
                                      ((unsigned int)f2bf(acc[m][j][3]) << 16);
                    uint2 pk; pk.x = lo; pk.y = hi;
                    *(uint2*)(part + (((size_t)ks * 64 + n) * 196 + p) * 128 + oc) = pk;
                }
            }
        }
    }
}

// stem1 reduce: sum 4 bf16 partials + bias + relu -> XA bf16 [n][p][128]
__global__ __launch_bounds__(256) void k_stem1r(const char* __restrict__ ws_c,
                                                const float* __restrict__ bias,
                                                unsigned short* __restrict__ xa)
{
    int i = blockIdx.x * 256 + threadIdx.x;        // 64*196*16
    const unsigned short* part = (const unsigned short*)(ws_c + B_S1P);
    int oc8 = (i & 15) * 8;
    int np  = i >> 4;                               // n*196+p
    float s[8] = {};
#pragma unroll
    for (int ks = 0; ks < 4; ++ks) {
        short8 v = *(const short8*)(part + (((size_t)ks * 64) * 196 + np) * 128 + oc8);
#pragma unroll
        for (int e = 0; e < 8; ++e) s[e] += bf2f((unsigned short)v[e]);
    }
    short8 o;
#pragma unroll
    for (int e = 0; e < 8; ++e)
        o[e] = (short)f2bf(fmaxf(s[e] + bias[oc8 + e], 0.f));
    *(short8*)(xa + (size_t)np * 128 + oc8) = o;
}

// ---------------------------------------------------------------------------
// MFMA 3x3 dilated conv core for 128-IC (stem2 + module rounds), unchanged.
// ---------------------------------------------------------------------------
__device__ void conv_mfma_core(const unsigned short* __restrict__ srcB,
                               const float*  __restrict__ gate,
                               const unsigned short* __restrict__ wrep,
                               const float*  __restrict__ bias,
                               unsigned short* __restrict__ dst,
                               int dil, int och, int pxh,
                               unsigned short* s_img)
{
    const int tid  = threadIdx.x, lane = tid & 63;
    const int w    = tid >> 6, wm = w & 1, wn = w >> 1;
    const int l15  = lane & 15, lq = lane >> 4;

    if (tid < 68) ((unsigned int*)s_img)[196 * 68 + tid] = 0u;   // zero page row

    int pglob[4], pbyt[4], pyv[4], pxv[4];
#pragma unroll
    for (int j = 0; j < 4; ++j) {
        int nt = wn + 2 * j;
        int p  = (pxh * 7 + nt) * 16 + l15;
        pglob[j] = p;
        int py = p / 14;
        pyv[j] = (p < 196) ? py : 10000;
        pxv[j] = p - py * 14;
        pbyt[j] = p * 272 + lq * 16;
    }
    const int zaddr = 196 * 272 + lq * 16;
    const int nNT = (wn == 0) ? 4 : 3;

    f32x4 acc[2][4];
#pragma unroll
    for (int m = 0; m < 2; ++m)
#pragma unroll
        for (int j = 0; j < 4; ++j) acc[m][j] = (f32x4){0.f, 0.f, 0.f, 0.f};

    if (gate) {
        for (int i = tid; i < 196 * 16; i += 256) {
            int p = i >> 4, c8 = (i & 15) * 8;
            short8 v = *(const short8*)(srcB + p * 128 + c8);
            float g = gate[p];
            short8 ov;
#pragma unroll
            for (int e = 0; e < 8; ++e)
                ov[e] = (short)f2bf(bf2f((unsigned short)v[e]) * g);
            *(short8*)(s_img + p * 136 + c8) = ov;
        }
    } else {
        for (int i = tid; i < 196 * 16; i += 256) {
            int p = i >> 4, c8 = (i & 15) * 8;
            *(short8*)(s_img + p * 136 + c8) = *(const short8*)(srcB + p * 128 + c8);
        }
    }
    __syncthreads();

    const unsigned short* wlane = wrep + (size_t)(och * 64 + wm * 32 + l15) * 128 + lq * 8;
#pragma unroll
    for (int t = 0; t < 9; ++t) {
        const int dy = (t / 3 - 1) * dil, dx = (t % 3 - 1) * dil;
        int baddr[4];
#pragma unroll
        for (int j = 0; j < 4; ++j) {
            int yy = pyv[j] + dy, xx = pxv[j] + dx;
            bool ok = ((unsigned)yy < 14u) && ((unsigned)xx < 14u);
            baddr[j] = ok ? (pbyt[j] + (dy * 14 + dx) * 272) : zaddr;
        }
        const unsigned short* wt = wlane + (size_t)(t * 128) * 128;
#pragma unroll
        for (int kc = 0; kc < 4; ++kc) {
            bf16x8 a0 = *(const bf16x8*)(wt + kc * 32);
            bf16x8 a1 = *(const bf16x8*)(wt + (size_t)16 * 128 + kc * 32);
#pragma unroll
            for (int j = 0; j < 4; ++j) {
                if (j < nNT) {
                    bf16x8 b = *(const bf16x8*)((const char*)s_img + baddr[j] + kc * 64);
                    acc[0][j] = mfma16(a0, b, acc[0][j]);
                    acc[1][j] = mfma16(a1, b, acc[1][j]);
                }
            }
        }
    }

    // epilogue: bias + relu -> bf16 [196][128]
#pragma unroll
    for (int m = 0; m < 2; ++m) {
        const int oc = och * 64 + wm * 32 + m * 16 + lq * 4;
        const float4 b4 = *(const float4*)(bias + oc);
#pragma unroll
        for (int j = 0; j < 4; ++j) {
            if (j < nNT) {
                int p = pglob[j];
                if (p < 196) {
                    float v0 = fmaxf(acc[m][j][0] + b4.x, 0.f);
                    float v1 = fmaxf(acc[m][j][1] + b4.y, 0.f);
                    float v2 = fmaxf(acc[m][j][2] + b4.z, 0.f);
                    float v3 = fmaxf(acc[m][j][3] + b4.w, 0.f);
                    unsigned int lo = (unsigned int)f2bf(v0) | ((unsigned int)f2bf(v1) << 16);
                    unsigned int hi = (unsigned int)f2bf(v2) | ((unsigned int)f2bf(v3) << 16);
                    uint2 pk; pk.x = lo; pk.y = hi;
                    *(uint2*)(dst + p * 128 + oc) = pk;
                }
            }
        }
    }
}

__global__ __launch_bounds__(256) void k_conv_stem2(const unsigned short* __restrict__ srcBall,
                                                    const unsigned short* __restrict__ wrep,
                                                    const float* __restrict__ bias,
                                                    unsigned short* __restrict__ dstall)
{
    __shared__ unsigned short s_img[197 * 136];
    const int n = blockIdx.x >> 2, och = (blockIdx.x >> 1) & 1, pxh = blockIdx.x & 1;
    conv_mfma_core(srcBall + (size_t)n * 25088, nullptr, wrep, bias,
                   dstall + (size_t)n * 25088, 1, och, pxh, s_img);
}

// ---------------------------------------------------------------------------
// Module interpreter round.
// ---------------------------------------------------------------------------
struct RArgs {
    char* ws;
    const float* mbias[9];
    const float* w1x1[2];
    const float* b1x1[2];
};

__global__ __launch_bounds__(256) void k_round(RArgs a, int r)
{
    __shared__ unsigned short s_img[197 * 136];
    const int bx = blockIdx.x;
    const int n = bx >> 2, och = (bx >> 1) & 1, pxh = bx & 1;
    char* ws = a.ws;
    const int* sched = (const int*)(ws + B_SCHED);
    const int e = sched[n * NROUNDS + r];
    const int op = e & 15;
    if (op == 0) return;
    float* attn  = (float*)(ws + B_ATTN)  + n * 196;
    float* saved = (float*)(ws + B_SAVED) + n * 196;
    if (op == 1 || op == 2) {
        if ((bx & 3) == 0 && threadIdx.x < 196) {
            int p = threadIdx.x;
            if (op == 1) { saved[p] = attn[p]; attn[p] = 1.0f; }
            else         attn[p] = fminf(attn[p], saved[p]);
        }
        return;
    }
    const int wset = (e >> 4) & 15, dil = (e >> 8) & 15, gatef = (e >> 12) & 1;
    const int srcid = (e >> 13) & 3, dstid = (e >> 15) & 3;
    const unsigned short* src = (const unsigned short*)(ws +
            (srcid == 3 ? B_STEM : srcid == 1 ? B_XB : B_XA)) + (size_t)n * 25088;
    if (op == 4) {                                  // conv1x1 + sigmoid -> attn
        if ((bx & 3) == 0 && threadIdx.x < 196) {
            int p = threadIdx.x;
            const float* wv = a.w1x1[wset];
            float acc = a.b1x1[wset][0];
            const unsigned short* row = src + p * 128;
#pragma unroll 8
            for (int ic = 0; ic < 128; ++ic) acc += bf2f(row[ic]) * wv[ic];
            attn[p] = 1.0f / (1.0f + __expf(-acc));
        }
        return;
    }
    unsigned short* dst = (unsigned short*)(ws +
            (dstid == 2 ? B_FEAT : dstid == 1 ? B_XB : B_XA)) + (size_t)n * 25088;
    const unsigned short* wrep = (const unsigned short*)(ws + B_WMOD) + (size_t)wset * 9 * 128 * 128;
    conv_mfma_core(src, gatef ? attn : nullptr, wrep, a.mbias[wset], dst,
                   dil, och, pxh, s_img);
}

// ---------------------------------------------------------------------------
// cls 1x1 conv (128->1024, MFMA) + bias + relu + 2x2 maxpool -> actB bf16
// in permuted fc1-B layout: for k: kb=k>>6, lq=(k>>4)&3, hi=(k>>3)&1, e=k&7
// offset = (((kb*4+lq)*2+hi)*64 + n)*8 + e.
// ---------------------------------------------------------------------------
__global__ __launch_bounds__(256) void k_cls_pool(const unsigned short* __restrict__ featall,
                                                  const unsigned short* __restrict__ clsw,
                                                  const float* __restrict__ clsb,
                                                  unsigned short* __restrict__ actB)
{
    __shared__ char smem[197 * 272 + 64 * 200 * 4];
    unsigned short* s_img = (unsigned short*)smem;
    float* s_pool = (float*)(smem + 197 * 272);
    const int n = blockIdx.x >> 4, pt = blockIdx.x & 15;
    const int tid = threadIdx.x, lane = tid & 63, w = tid >> 6;
    const int l15 = lane & 15, lq = lane >> 4;
    const unsigned short* feat = featall + (size_t)n * 25088;

    if (tid < 68) ((unsigned int*)s_img)[196 * 68 + tid] = 0u;
    for (int i = tid; i < 196 * 16; i += 256) {
        int p = i >> 4, c8 = (i & 15) * 8;
        *(short8*)(s_img + p * 136 + c8) = *(const short8*)(feat + p * 128 + c8);
    }
    f32x4 acc[14];
#pragma unroll
    for (int j = 0; j < 14; ++j) acc[j] = (f32x4){0.f, 0.f, 0.f, 0.f};
    __syncthreads();

    const unsigned short* wl = clsw + (size_t)(pt * 64 + w * 16 + l15) * 128 + lq * 8;
#pragma unroll
    for (int kc = 0; kc < 4; ++kc) {
        bf16x8 a0 = *(const bf16x8*)(wl + kc * 32);
#pragma unroll
        for (int j = 0; j < 14; ++j) {
            int p = j * 16 + l15;
            int ba = (p < 196) ? (p * 272 + lq * 16 + kc * 64) : (196 * 272 + lq * 16);
            bf16x8 b = *(const bf16x8*)((const char*)s_img + ba);
            acc[j] = mfma16(a0, b, acc[j]);
        }
    }
    const int oc = pt * 64 + w * 16 + lq * 4;
    const float4 b4 = *(const float4*)(clsb + oc);
    const int pl = w * 16 + lq * 4;
#pragma unroll
    for (int j = 0; j < 14; ++j) {
        int p = j * 16 + l15;
        if (p < 196) {
            s_pool[(pl + 0) * 200 + p] = fmaxf(acc[j][0] + b4.x, 0.f);
            s_pool[(pl + 1) * 200 + p] = fmaxf(acc[j][1] + b4.y, 0.f);
            s_pool[(pl + 2) * 200 + p] = fmaxf(acc[j][2] + b4.z, 0.f);
            s_pool[(pl + 3) * 200 + p] = fmaxf(acc[j][3] + b4.w, 0.f);
        }
    }
    __syncthreads();
    for (int i = tid; i < 64 * 49; i += 256) {
        int plx = i / 49, q = i - plx * 49;
        int py = q / 7, qx = q - py * 7;
        const float* rp = s_pool + plx * 200 + py * 28 + qx * 2;
        float m = fmaxf(fmaxf(rp[0], rp[1]), fmaxf(rp[14], rp[15]));
        int k = (pt * 64 + plx) * 49 + q;
        int kb = k >> 6, lq2 = (k >> 4) & 3, hi = (k >> 3) & 1, e = k & 7;
        actB[((((size_t)kb * 4 + lq2) * 2 + hi) * 64 + n) * 8 + e] = f2bf(m);
    }
}

// ---------------------------------------------------------------------------
// fc1 partial GEMM: per 64-k step each lane reads 64B contiguous W (4 float4),
// B from permuted actB. Grid: blockIdx = ks*16 + jt (ks 0..48).
// ---------------------------------------------------------------------------
__global__ __launch_bounds__(256) void k_fc1p(const unsigned short* __restrict__ actB,
                                              const float* __restrict__ w,
                                              float* __restrict__ part)
{
    const int jt = blockIdx.x & 15, ks = blockIdx.x >> 4;
    const int tid = threadIdx.x, lane = tid & 63, wv = tid >> 6;
    const int l15 = lane & 15, lq = lane >> 4;
    const int k0 = ks * 1024;
    const int j = jt * 64 + wv * 16 + l15;

    f32x4 acc[4];
#pragma unroll
    for (int t = 0; t < 4; ++t) acc[t] = (f32x4){0.f, 0.f, 0.f, 0.f};

    const float* wrow = w + (size_t)j * 50176 + k0 + lq * 16;
    const int kb0 = k0 >> 6;

#pragma unroll 4
    for (int kc = 0; kc < 1024; kc += 64) {
        const float* wp = wrow + kc;
        float4 f0 = *(const float4*)(wp);
        float4 f1 = *(const float4*)(wp + 4);
        float4 f2 = *(const float4*)(wp + 8);
        float4 f3 = *(const float4*)(wp + 12);
        bf16x8 a0, a1;
        a0[0] = (__bf16)f0.x; a0[1] = (__bf16)f0.y; a0[2] = (__bf16)f0.z; a0[3] = (__bf16)f0.w;
        a0[4] = (__bf16)f1.x; a0[5] = (__bf16)f1.y; a0[6] = (__bf16)f1.z; a0[7] = (__bf16)f1.w;
        a1[0] = (__bf16)f2.x; a1[1] = (__bf16)f2.y; a1[2] = (__bf16)f2.z; a1[3] = (__bf16)f2.w;
        a1[4] = (__bf16)f3.x; a1[5] = (__bf16)f3.y; a1[6] = (__bf16)f3.z; a1[7] = (__bf16)f3.w;
        const int kb = kb0 + (kc >> 6);
        const unsigned short* bp0 = actB + (((size_t)kb * 4 + lq) * 2) * 512 + l15 * 8;
#pragma unroll
        for (int t = 0; t < 4; ++t) {
            bf16x8 b0 = *(const bf16x8*)(bp0 + t * 128);
            bf16x8 b1 = *(const bf16x8*)(bp0 + 512 + t * 128);
            acc[t] = mfma16(a0, b0, acc[t]);
            acc[t] = mfma16(a1, b1, acc[t]);
        }
    }

    float* pbase = part + ((size_t)ks * 1024 + jt * 64 + wv * 16 + lq * 4) * 64 + l15;
#pragma unroll
    for (int t = 0; t < 4; ++t)
#pragma unroll
        for (int r = 0; r < 4; ++r)
            pbase[(size_t)r * 64 + t * 16] = acc[t][r];
}

__global__ __launch_bounds__(256) void k_fc1r(const float* __restrict__ part,
                                              const float* __restrict__ b,
                                              float* __restrict__ fc1T)
{
    int i = blockIdx.x * 256 + threadIdx.x;
    if (i >= 65536) return;
    float s = 0.0f;
    for (int ks = 0; ks < NKS; ++ks) s += part[(size_t)ks * 65536 + i];
    int j = i >> 6;
    fc1T[i] = fmaxf(s + b[j], 0.0f);
}

__global__ __launch_bounds__(256) void k_fc2(const float* __restrict__ fc1T,
                                             const float* __restrict__ w,
                                             const float* __restrict__ b,
                                             float* __restrict__ out)
{
    __shared__ float red[256];
    const int a_ = blockIdx.x;
    const int tid = threadIdx.x, lane = tid & 63, q = tid >> 6;
    float acc = 0.0f;
    const float* wr = w + (size_t)a_ * 1024;
    for (int k = q * 256; k < q * 256 + 256; ++k)
        acc = fmaf(fc1T[k * 64 + lane], wr[k], acc);
    red[tid] = acc;
    __syncthreads();
    if (q == 0) {
        float s = red[tid] + red[tid + 64] + red[tid + 128] + red[tid + 192] + b[a_];
        out[lane * 28 + a_] = s;
    }
}

extern "C" void kernel_launch(void* const* d_in, const int* in_sizes, int n_in,
                              void* d_out, int out_size, void* d_ws, size_t ws_size,
                              hipStream_t stream)
{
    const float* feats = (const float*)d_in[0];
    const int*   prog  = (const int*)d_in[1];
    char* ws  = (char*)d_ws;
    float* out = (float*)d_out;

    RepackArgs ra;
    ra.src[0]  = (const float*)d_in[2];   // stem_w1
    ra.src[1]  = (const float*)d_in[4];   // stem_w2
    ra.src[2]  = (const float*)d_in[6];   // att_w1
    ra.src[3]  = (const float*)d_in[8];   // att_w2
    ra.src[4]  = (const float*)d_in[12];  // rel_w1
    ra.src[5]  = (const float*)d_in[14];  // rel_w2
    ra.src[6]  = (const float*)d_in[16];  // rel_w3
    ra.src[7]  = (const float*)d_in[18];  // rel_w4
    ra.src[8]  = (const float*)d_in[20];  // rel_w5
    ra.src[9]  = (const float*)d_in[24];  // qry_w1
    ra.src[10] = (const float*)d_in[26];  // qry_w2
    ra.src[11] = (const float*)d_in[28];  // cls_w

    k_repack<<<dim3(64, 12), 256, 0, stream>>>(ra, ws);

    // stem1: feats(f32) -> partials -> XA
    k_stem1p<<<1024, 256, 0, stream>>>(feats, (const unsigned short*)(ws + B_WSTEM1), ws);
    k_stem1r<<<784, 256, 0, stream>>>(ws, (const float*)d_in[3],
                                      (unsigned short*)(ws + B_XA));

    k_decode_init<<<256, 256, 0, stream>>>(prog, ws);   // after stem1r (FEAT overlay)

    // stem2: XA -> STEM
    k_conv_stem2<<<256, 256, 0, stream>>>((const unsigned short*)(ws + B_XA),
                                          (const unsigned short*)(ws + B_WSTEM2),
                                          (const float*)d_in[5],
                                          (unsigned short*)(ws + B_STEM));

    RArgs ga;
    ga.ws = ws;
    ga.mbias[0] = (const float*)d_in[7];   // att_b1
    ga.mbias[1] = (const float*)d_in[9];   // att_b2
    ga.mbias[2] = (const float*)d_in[13];  // rel_b1
    ga.mbias[3] = (const float*)d_in[15];  // rel_b2
    ga.mbias[4] = (const float*)d_in[17];  // rel_b3
    ga.mbias[5] = (const float*)d_in[19];  // rel_b4
    ga.mbias[6] = (const float*)d_in[21];  // rel_b5
    ga.mbias[7] = (const float*)d_in[25];  // qry_b1
    ga.mbias[8] = (const float*)d_in[27];  // qry_b2
    ga.w1x1[0]  = (const float*)d_in[10];  // att_w3
    ga.w1x1[1]  = (const float*)d_in[22];  // rel_w6
    ga.b1x1[0]  = (const float*)d_in[11];  // att_b3
    ga.b1x1[1]  = (const float*)d_in[23];  // rel_b6

    for (int r = 0; r < NROUNDS; ++r)
        k_round<<<256, 256, 0, stream>>>(ga, r);

    k_cls_pool<<<1024, 256, 0, stream>>>((const unsigned short*)(ws + B_FEAT),
                                         (const unsigned short*)(ws + B_WCLS),
                                         (const float*)d_in[29],
                                         (unsigned short*)(ws + B_ACTB));
    k_fc1p<<<784, 256, 0, stream>>>((const unsigned short*)(ws + B_ACTB),
                                    (const float*)d_in[30], (float*)(ws + B_FC1P));
    k_fc1r<<<256, 256, 0, stream>>>((const float*)(ws + B_FC1P), (const float*)d_in[31],
                                    (float*)(ws + B_FC1T));
    k_fc2<<<28, 256, 0, stream>>>((const float*)(ws + B_FC1T), (const float*)d_in[32],
                                  (const float*)d_in[33], out);
}